// Round 5
// baseline (511.361 us; speedup 1.0000x reference)
//
#include <hip/hip_runtime.h>
#include <hip/hip_bf16.h>
#include <stdint.h>

#define NBATCH 16
#define SEQ    2048
#define DMODEL 1024
#define KSPLIT 8

typedef __attribute__((ext_vector_type(8))) short short8;   // 8 bf16 = 4 VGPRs
typedef __attribute__((ext_vector_type(4))) float f32x4;

struct __align__(8) bf4 { __hip_bfloat16 h[4]; };

__device__ __forceinline__ float bf2f(short s) {
  union { uint32_t u; float f; } c;
  c.u = ((uint32_t)(uint16_t)s) << 16;
  return c.f;
}

// async global -> LDS, 16B/lane. LDS dest = wave-uniform base + lane*16.
__device__ __forceinline__ void gload16(const void* g, void* l) {
  __builtin_amdgcn_global_load_lds(
      (const __attribute__((address_space(1))) void*)g,
      (__attribute__((address_space(3))) void*)l, 16, 0, 0);
}

#define BAR() __builtin_amdgcn_s_barrier()
#define WAIT_LGKM0()                                         \
  do {                                                       \
    asm volatile("s_waitcnt lgkmcnt(0)" ::: "memory");       \
    __builtin_amdgcn_sched_barrier(0);                       \
  } while (0)
#define WAIT_VM0()                                           \
  do {                                                       \
    asm volatile("s_waitcnt vmcnt(0)" ::: "memory");         \
  } while (0)

// ---------------------------------------------------------------------------
// 256x256-tile 8-wave GEMM, BK=64, dbuf 128KiB LDS, T2 swizzle, 8-phase.
// Computes OUT[Brow][Arow] = sum_e A[Arow][e]*B[Brow][e]  (A,B row-major,
// ld = DMODEL, K = DMODEL).  Arow is the contiguous OUT dim -> j-packed 8B
// stores (MFMA D-row dim (g*4+j) follows the FIRST operand's tile rows).
// MODE 0: plain bf16 OUT (ldo param). grid (ATILES, BTILES).
// MODE 1: E[q][k] epilogue: e = mask[k] ? exp((s+v[k])/32) : 0, Zpart[q].
//         grid (64 = bt2&7 + 8*at2, nb).
template <int MODE>
__global__ __launch_bounds__(512, 2)
void gemmT_kernel(const __hip_bfloat16* __restrict__ Aall,
                  const __hip_bfloat16* __restrict__ Ball,
                  __hip_bfloat16* __restrict__ OUT, int ldo,
                  const int* __restrict__ mask,
                  const float* __restrict__ vball,
                  float* __restrict__ Zpart, int b0) {
  __shared__ __align__(16) char smem[131072];
  const int t = threadIdx.x, lane = t & 63, wid = t >> 6;
  const int wm = wid >> 2, wn = wid & 3;
  const int g = lane >> 4, l15 = lane & 15, l7 = lane & 7;

  const __hip_bfloat16 *Ab, *Bb;
  int at2, bt2, cb = 0;
  if constexpr (MODE == 0) {
    at2 = blockIdx.x; bt2 = blockIdx.y;
    Ab = Aall + (size_t)at2 * 256 * DMODEL;
    Bb = Ball + (size_t)bt2 * 256 * DMODEL;
  } else {
    cb = blockIdx.y;
    bt2 = blockIdx.x & 7;       // q-tile; bx%8 -> XCD shares B(Y) panel
    at2 = blockIdx.x >> 3;      // k-tile
    Ab = Aall + ((size_t)(b0 + cb) * SEQ + at2 * 256) * DMODEL;
    Bb = Ball + ((size_t)(b0 + cb) * SEQ + bt2 * 256) * DMODEL;
  }

  char* bufA[2] = {smem, smem + 65536};
  char* bufB[2] = {smem + 32768, smem + 98304};

  const int srl = t >> 3;
  const int sc8 = (t & 7) ^ (srl & 7);          // pre-swizzled global col8
  const int pc8[2] = {g ^ l7, (4 + g) ^ l7};    // swizzled read col8

  auto stage_mat = [&](const __hip_bfloat16* gs, char* dst, int kt) {
#pragma unroll
    for (int h = 0; h < 2; ++h)
#pragma unroll
      for (int it = 0; it < 2; ++it)
        gload16(gs + (size_t)(h * 128 + it * 64 + srl) * DMODEL + kt * 64 + sc8 * 8,
                dst + h * 16384 + it * 8192 + wid * 1024);
  };

  f32x4 acc[8][4];
#pragma unroll
  for (int m = 0; m < 8; ++m)
#pragma unroll
    for (int n = 0; n < 4; ++n) acc[m][n] = (f32x4){0.f, 0.f, 0.f, 0.f};
  short8 afr[2][4], bfr[2][2][2];

#define LDA_Q(MH)                                                           \
  { _Pragma("unroll") for (int m = 0; m < 4; ++m) {                         \
      const int row = wm * 128 + ((MH) * 4 + m) * 16 + l15;                 \
      afr[0][m] = *(const short8*)(At + row * 128 + pc8[0] * 16);           \
      afr[1][m] = *(const short8*)(At + row * 128 + pc8[1] * 16);           \
    } }
#define LDB_Q(NH)                                                           \
  { _Pragma("unroll") for (int n = 0; n < 2; ++n) {                         \
      const int row = wn * 64 + ((NH) * 2 + n) * 16 + l15;                  \
      bfr[NH][0][n] = *(const short8*)(Bt + row * 128 + pc8[0] * 16);       \
      bfr[NH][1][n] = *(const short8*)(Bt + row * 128 + pc8[1] * 16);       \
    } }
#define MFMA_Q(MH, NH)                                                      \
  { __builtin_amdgcn_s_setprio(1);                                          \
    _Pragma("unroll") for (int kk = 0; kk < 2; ++kk)                        \
    _Pragma("unroll") for (int m = 0; m < 4; ++m)                           \
    _Pragma("unroll") for (int n = 0; n < 2; ++n)                           \
      acc[(MH)*4+m][(NH)*2+n] = __builtin_amdgcn_mfma_f32_16x16x32_bf16(    \
          afr[kk][m], bfr[NH][kk][n], acc[(MH)*4+m][(NH)*2+n], 0, 0, 0);    \
    __builtin_amdgcn_s_setprio(0); }

  stage_mat(Ab, bufA[0], 0);
  stage_mat(Bb, bufB[0], 0);
  WAIT_VM0();
  BAR();

  const char *At, *Bt;
#pragma unroll 1
  for (int i = 0; i < 8; ++i) {
    At = bufA[0]; Bt = bufB[0];
    LDA_Q(0) LDB_Q(0)
    stage_mat(Ab, bufA[1], 2 * i + 1);
    BAR(); WAIT_LGKM0(); MFMA_Q(0, 0) BAR();
    LDB_Q(1)
    stage_mat(Bb, bufB[1], 2 * i + 1);
    BAR(); WAIT_LGKM0(); MFMA_Q(0, 1) BAR();
    LDA_Q(1)
    BAR(); WAIT_LGKM0(); MFMA_Q(1, 0) BAR();
    MFMA_Q(1, 1)
    WAIT_VM0();
    BAR();
    At = bufA[1]; Bt = bufB[1];
    LDA_Q(0) LDB_Q(0)
    if (i < 7) stage_mat(Ab, bufA[0], 2 * i + 2);
    BAR(); WAIT_LGKM0(); MFMA_Q(0, 0) BAR();
    LDB_Q(1)
    if (i < 7) stage_mat(Bb, bufB[0], 2 * i + 2);
    BAR(); WAIT_LGKM0(); MFMA_Q(0, 1) BAR();
    LDA_Q(1)
    BAR(); WAIT_LGKM0(); MFMA_Q(1, 0) BAR();
    MFMA_Q(1, 1)
    WAIT_VM0();
    BAR();
  }
#undef LDA_Q
#undef LDB_Q
#undef MFMA_Q

  if constexpr (MODE == 0) {
    const size_t orow0 = (size_t)bt2 * 256 + wn * 64 + l15;
    const int ocol0 = at2 * 256 + wm * 128 + g * 4;
#pragma unroll
    for (int mi = 0; mi < 8; ++mi)
#pragma unroll
      for (int ni = 0; ni < 4; ++ni) {
        bf4 pk;
#pragma unroll
        for (int j = 0; j < 4; ++j) pk.h[j] = __float2bfloat16(acc[mi][ni][j]);
        *(bf4*)(OUT + (orow0 + ni * 16) * ldo + ocol0 + mi * 16) = pk;
      }
  } else {
    const int b = b0 + cb;
    const int kb = at2 * 256 + wm * 128 + g * 4;
    const int qb = bt2 * 256 + wn * 64 + l15;
    float zc[4] = {0.f, 0.f, 0.f, 0.f};
#pragma unroll
    for (int mi = 0; mi < 8; ++mi) {
      const int k0 = kb + mi * 16;
      const int4 mk4 = *(const int4*)&mask[(size_t)b * SEQ + k0];
      const float4 v4 = *(const float4*)&vball[(size_t)b * SEQ + k0];
#pragma unroll
      for (int ni = 0; ni < 4; ++ni) {
        bf4 pk;
#pragma unroll
        for (int j = 0; j < 4; ++j) {
          const int km = (j == 0) ? mk4.x : (j == 1) ? mk4.y : (j == 2) ? mk4.z : mk4.w;
          const float vj = (j == 0) ? v4.x : (j == 1) ? v4.y : (j == 2) ? v4.z : v4.w;
          const float ev = km ? __expf((acc[mi][ni][j] + vj) * 0.03125f) : 0.f;
          zc[ni] += ev;
          pk.h[j] = __float2bfloat16(ev);
        }
        *(bf4*)(OUT + ((size_t)cb * SEQ + qb + ni * 16) * (size_t)SEQ + k0) = pk;
      }
    }
#pragma unroll
    for (int ni = 0; ni < 4; ++ni) {
      float v = zc[ni];
      v += __shfl_xor(v, 16);
      v += __shfl_xor(v, 32);
      zc[ni] = v;
    }
    float* red = (float*)smem;  // [2][256]; tiles dead
    if (lane < 16) {
#pragma unroll
      for (int ni = 0; ni < 4; ++ni)
        red[wm * 256 + wn * 64 + ni * 16 + lane] = zc[ni];
    }
    __syncthreads();
    if (t < 256)
      Zpart[((size_t)cb * 8 + at2) * SEQ + bt2 * 256 + t] = red[t] + red[256 + t];
  }
}

// ---------------------------------------------------------------------------
// fp32 [DMODEL][DMODEL] -> bf16 transposed
__global__ void transpose_cvt_kernel(const float* __restrict__ in,
                                     __hip_bfloat16* __restrict__ outp) {
  __shared__ float tile[32][33];
  const int bx = blockIdx.x, by = blockIdx.y;
  const int tx = threadIdx.x & 31, ty = threadIdx.x >> 5;  // 32 x 8
#pragma unroll
  for (int r = 0; r < 32; r += 8)
    tile[ty + r][tx] = in[(size_t)(by * 32 + ty + r) * DMODEL + bx * 32 + tx];
  __syncthreads();
#pragma unroll
  for (int r = 0; r < 32; r += 8)
    outp[(size_t)(bx * 32 + ty + r) * DMODEL + by * 32 + tx] =
        __float2bfloat16(tile[tx][ty + r]);
}

// t2[d] = sum_e Wk[e][d]*bq[e]  (via WkT rows)
__global__ __launch_bounds__(256)
void prep_t2_kernel(const __hip_bfloat16* __restrict__ WkT,
                    const float* __restrict__ bq, float* __restrict__ t2) {
  const int wave = threadIdx.x >> 6, lane = threadIdx.x & 63;
  const int d = blockIdx.x * 4 + wave;
  const short8* kr = (const short8*)(WkT + (size_t)d * DMODEL);
  float a2 = 0.f;
#pragma unroll
  for (int h = 0; h < 2; ++h) {
    const short8 kv = kr[lane * 2 + h];
    const int e0 = lane * 16 + h * 8;
#pragma unroll
    for (int i = 0; i < 8; ++i) a2 += bf2f(kv[i]) * bq[e0 + i];
  }
  a2 += __shfl_down(a2, 32); a2 += __shfl_down(a2, 16); a2 += __shfl_down(a2, 8);
  a2 += __shfl_down(a2, 4);  a2 += __shfl_down(a2, 2);  a2 += __shfl_down(a2, 1);
  if (lane == 0) t2[d] = a2;
}

// fused: x fp32 -> x_bf (all batches) + vb[row] = x[row].t2
__global__ __launch_bounds__(256)
void cvtv_kernel(const float* __restrict__ x, const float* __restrict__ t2,
                 __hip_bfloat16* __restrict__ x_bf, float* __restrict__ vb) {
  const int wave = threadIdx.x >> 6, lane = threadIdx.x & 63;
  const size_t row = (size_t)blockIdx.x * 4 + wave;
  const float* xr = x + row * DMODEL;
  float a2 = 0.f;
#pragma unroll
  for (int p = 0; p < 4; ++p) {
    const int d = p * 256 + lane * 4;
    const float4 xv = *(const float4*)(xr + d);
    const float4 tv = *(const float4*)(t2 + d);
    a2 += xv.x * tv.x + xv.y * tv.y + xv.z * tv.z + xv.w * tv.w;
    bf4 pk;
    pk.h[0] = __float2bfloat16(xv.x); pk.h[1] = __float2bfloat16(xv.y);
    pk.h[2] = __float2bfloat16(xv.z); pk.h[3] = __float2bfloat16(xv.w);
    *(bf4*)(x_bf + row * DMODEL + d) = pk;
  }
  a2 += __shfl_down(a2, 32); a2 += __shfl_down(a2, 16); a2 += __shfl_down(a2, 8);
  a2 += __shfl_down(a2, 4);  a2 += __shfl_down(a2, 2);  a2 += __shfl_down(a2, 1);
  if (lane == 0) vb[row] = a2;
}

// rZ[cb][q] = 1 / sum_{at2<8} Zpart[cb][at2][q]  (0 if empty)
__global__ void zinv_kernel(const float* __restrict__ Zpart,
                            float* __restrict__ rZ, int n) {
  const int idx = blockIdx.x * 256 + threadIdx.x;
  if (idx >= n) return;
  const int cb = idx >> 11, q = idx & (SEQ - 1);
  float z = 0.f;
#pragma unroll
  for (int kt = 0; kt < 8; ++kt)
    z += Zpart[((size_t)cb * 8 + kt) * SEQ + q];
  rZ[(size_t)cb * SEQ + q] = (z > 0.f) ? (1.f / z) : 0.f;
}

// passB: wpart[cb][qs][k] = sum_{q in slice} rZ[q] * E[q][k]
// grid (64 = qs&15 + 16*ks, nb); 256 thr, 2 k per thread.
__global__ __launch_bounds__(256)
void passB_kernel(const __hip_bfloat16* __restrict__ E,
                  const float* __restrict__ rZ,
                  float* __restrict__ wpart) {
  const int cb = blockIdx.y;
  const int qs = blockIdx.x & 15, ks = blockIdx.x >> 4;
  const int k2 = ks * 256 + threadIdx.x;  // uint32 index (2 bf16)
  const uint32_t* Ep = (const uint32_t*)(E + (size_t)cb * SEQ * SEQ);
  const float* rz = rZ + (size_t)cb * SEQ + qs * 128;
  float a0 = 0.f, a1 = 0.f;
#pragma unroll 4
  for (int qq = 0; qq < 128; ++qq) {
    const float r = rz[qq];
    const uint32_t pv = Ep[(size_t)(qs * 128 + qq) * (SEQ / 2) + k2];
    a0 += r * bf2f((short)(pv & 0xffff));
    a1 += r * bf2f((short)(pv >> 16));
  }
  float2* o = (float2*)&wpart[((size_t)cb * 16 + qs) * SEQ + 2 * k2];
  *o = make_float2(a0, a1);
}

// w[k] = sum_qs wpart; also per-block partial sums of w
__global__ __launch_bounds__(256)
void wreduce_kernel(const float* __restrict__ wpart,
                    float* __restrict__ wbuf, float* __restrict__ sumwp,
                    int b0) {
  __shared__ float sred[4];
  const int cb = blockIdx.y, bx = blockIdx.x;
  const int tdx = threadIdx.x, lane = tdx & 63, wave = tdx >> 6;
  const int k = bx * 256 + tdx;
  float w = 0.f;
#pragma unroll
  for (int qs = 0; qs < 16; ++qs)
    w += wpart[((size_t)cb * 16 + qs) * SEQ + k];
  wbuf[(size_t)cb * SEQ + k] = w;
  float v = w;
  v += __shfl_down(v, 32); v += __shfl_down(v, 16); v += __shfl_down(v, 8);
  v += __shfl_down(v, 4);  v += __shfl_down(v, 2);  v += __shfl_down(v, 1);
  if (lane == 0) sred[wave] = v;
  __syncthreads();
  if (tdx == 0)
    sumwp[(b0 + cb) * 8 + bx] = sred[0] + sred[1] + sred[2] + sred[3];
}

// wxp[kq][b][d] = sum_{k in chunk kq} w[k] * x_bf[b][k][d]
__global__ void wxpart_kernel(const __hip_bfloat16* __restrict__ x_bf,
                              const float* __restrict__ w,
                              float* __restrict__ wxp, int b0) {
  const int dt = blockIdx.x, cb = blockIdx.y, kq = blockIdx.z;
  const int b = b0 + cb;
  const int dp = dt * 256 + threadIdx.x;
  const __hip_bfloat16* xb =
      x_bf + ((size_t)b * SEQ + (size_t)kq * (SEQ / KSPLIT)) * DMODEL;
  const float* wb = w + (size_t)cb * SEQ + (size_t)kq * (SEQ / KSPLIT);
  float a0 = 0.f, a1 = 0.f;
#pragma unroll 4
  for (int k = 0; k < SEQ / KSPLIT; ++k) {
    const float wk = wb[k];
    const uint32_t pv = *(const uint32_t*)(xb + (size_t)k * DMODEL + dp * 2);
    a0 += wk * bf2f((short)(pv & 0xffff));
    a1 += wk * bf2f((short)(pv >> 16));
  }
  float2* o = (float2*)&wxp[((size_t)kq * NBATCH + b) * DMODEL + dp * 2];
  *o = make_float2(a0, a1);
}

// out[b][e] = ( sum_d (sum_kq wxp[kq][b][d]) * Wv[e][d] + sumw[b]*bv[e] ) / SEQ
__global__ void final_kernel(const float* __restrict__ wxp,
                             const float* __restrict__ sumwp,
                             const float* __restrict__ Wv,
                             const float* __restrict__ bv,
                             float* __restrict__ out) {
  const int b = blockIdx.y, eg = blockIdx.x;
  const int wave = threadIdx.x >> 6, lane = threadIdx.x & 63;
  const int e = eg * 4 + wave;
  float acc = 0.f;
  for (int d = lane; d < DMODEL; d += 64) {
    float wx = 0.f;
#pragma unroll
    for (int kq = 0; kq < KSPLIT; ++kq)
      wx += wxp[((size_t)kq * NBATCH + b) * DMODEL + d];
    acc += wx * Wv[(size_t)e * DMODEL + d];
  }
  acc += __shfl_down(acc, 32); acc += __shfl_down(acc, 16);
  acc += __shfl_down(acc, 8);  acc += __shfl_down(acc, 4);
  acc += __shfl_down(acc, 2);  acc += __shfl_down(acc, 1);
  if (lane == 0) {
    float sw = 0.f;
#pragma unroll
    for (int i = 0; i < 8; ++i) sw += sumwp[b * 8 + i];
    out[(size_t)b * DMODEL + e] = (acc + sw * bv[e]) * (1.f / (float)SEQ);
  }
}

// ---------------------------------------------------------------------------
extern "C" void kernel_launch(void* const* d_in, const int* in_sizes, int n_in,
                              void* d_out, int out_size, void* d_ws, size_t ws_size,
                              hipStream_t stream) {
  const float* x  = (const float*)d_in[0];
  const int* mask = (const int*)d_in[1];
  const float* Wq = (const float*)d_in[2];
  const float* bq = (const float*)d_in[3];
  const float* Wk = (const float*)d_in[4];
  const float* bk = (const float*)d_in[5];
  const float* Wv = (const float*)d_in[6];
  const float* bv = (const float*)d_in[7];
  float* out = (float*)d_out;
  (void)bk;

  char* ws = (char*)d_ws;
  size_t off = 0;
  auto alloc = [&](size_t bytes) -> void* {
    void* p = ws + off;
    off += (bytes + 255) & ~(size_t)255;
    return p;
  };
  // ---- persistent ----
  __hip_bfloat16* Mt_bf  = (__hip_bfloat16*)alloc((size_t)DMODEL * DMODEL * 2);
  __hip_bfloat16* WqT_bf = (__hip_bfloat16*)alloc((size_t)DMODEL * DMODEL * 2);
  __hip_bfloat16* WkT_bf = (__hip_bfloat16*)alloc((size_t)DMODEL * DMODEL * 2);
  float* wxp   = (float*)alloc((size_t)KSPLIT * NBATCH * DMODEL * 4);
  float* sumwp = (float*)alloc((size_t)NBATCH * 8 * 4);
  float* t2    = (float*)alloc((size_t)DMODEL * 4);
  __hip_bfloat16* x_bf = (__hip_bfloat16*)alloc((size_t)NBATCH * SEQ * DMODEL * 2);
  __hip_bfloat16* Yb   = (__hip_bfloat16*)alloc((size_t)NBATCH * SEQ * DMODEL * 2);
  float* vb = (float*)alloc((size_t)NBATCH * SEQ * 4);
  const size_t fixed = off;

  // ---- per-chunk ----
  const size_t per_batch = (size_t)SEQ * SEQ * 2       // E
                         + (size_t)8 * SEQ * 4         // Zpart
                         + (size_t)16 * SEQ * 4        // wpart
                         + (size_t)2 * SEQ * 4 + 8 * 256;
  long avail = (long)ws_size - (long)fixed;
  int NB = (int)(avail / (long)per_batch);
  if (NB < 1) NB = 1;
  if (NB > 4) NB = 4;
  while (NBATCH % NB) --NB;   // NB in {1,2,4}
  __hip_bfloat16* Ebuf = (__hip_bfloat16*)alloc((size_t)NB * SEQ * SEQ * 2);
  float* Zpart = (float*)alloc((size_t)NB * 8 * SEQ * 4);
  float* wpart = (float*)alloc((size_t)NB * 16 * SEQ * 4);
  float* rZ    = (float*)alloc((size_t)NB * SEQ * 4);
  float* wbuf  = (float*)alloc((size_t)NB * SEQ * 4);

  // ---- prep ----
  transpose_cvt_kernel<<<dim3(32, 32), dim3(256), 0, stream>>>(Wq, WqT_bf);
  transpose_cvt_kernel<<<dim3(32, 32), dim3(256), 0, stream>>>(Wk, WkT_bf);
  // Mt[d'][d] = sum_e WkT[d'][e]*WqT[d][e]   (A=WqT -> d contiguous)
  gemmT_kernel<0><<<dim3(4, 4), dim3(512), 0, stream>>>(
      WqT_bf, WkT_bf, Mt_bf, DMODEL, nullptr, nullptr, nullptr, 0);
  prep_t2_kernel<<<dim3(256), dim3(256), 0, stream>>>(WkT_bf, bq, t2);
  cvtv_kernel<<<dim3(NBATCH * SEQ / 4), dim3(256), 0, stream>>>(x, t2, x_bf, vb);
  // Y[q][d'] = sum_d x[q][d]*Mt[d'][d]   (A=Mt -> d' contiguous)
  gemmT_kernel<0><<<dim3(4, NBATCH * 8), dim3(512), 0, stream>>>(
      Mt_bf, x_bf, Yb, DMODEL, nullptr, nullptr, nullptr, 0);

  for (int b0 = 0; b0 < NBATCH; b0 += NB) {
    const int nb = NB;
    // E[q][k] = mask[k]?exp((Y[q].x[k] + v[k])/32):0 ; Zpart
    gemmT_kernel<1><<<dim3(64, nb), dim3(512), 0, stream>>>(
        x_bf, Yb, Ebuf, SEQ, mask, vb, Zpart, b0);
    zinv_kernel<<<dim3((nb * SEQ + 255) / 256), dim3(256), 0, stream>>>(
        Zpart, rZ, nb * SEQ);
    passB_kernel<<<dim3(64, nb), dim3(256), 0, stream>>>(Ebuf, rZ, wpart);
    wreduce_kernel<<<dim3(8, nb), dim3(256), 0, stream>>>(
        wpart, wbuf, sumwp, b0);
    wxpart_kernel<<<dim3(DMODEL / 512, nb, KSPLIT), dim3(256), 0, stream>>>(
        x_bf, wbuf, wxp, b0);
  }
  final_kernel<<<dim3(DMODEL / 4, NBATCH), dim3(256), 0, stream>>>(
      wxp, sumwp, Wv, bv, out);
}

// Round 6
// 391.287 us; speedup vs baseline: 1.3069x; 1.3069x over previous
//
#include <hip/hip_runtime.h>
#include <hip/hip_bf16.h>
#include <stdint.h>

#define NBATCH 16
#define SEQ    2048
#define DMODEL 1024
#define KSPLIT 8

typedef __attribute__((ext_vector_type(8))) short short8;   // 8 bf16 = 4 VGPRs
typedef __attribute__((ext_vector_type(4))) float f32x4;

struct __align__(8) bf4 { __hip_bfloat16 h[4]; };

__device__ __forceinline__ float bf2f(short s) {
  union { uint32_t u; float f; } c;
  c.u = ((uint32_t)(uint16_t)s) << 16;
  return c.f;
}
__device__ __forceinline__ short f2bfbits(float f) {
  union { __hip_bfloat16 h; short s; } u;
  u.h = __float2bfloat16(f);
  return u.s;
}

// async global -> LDS, 16B/lane. LDS dest = wave-uniform base + lane*16.
__device__ __forceinline__ void gload16(const void* g, void* l) {
  __builtin_amdgcn_global_load_lds(
      (const __attribute__((address_space(1))) void*)g,
      (__attribute__((address_space(3))) void*)l, 16, 0, 0);
}

#define BAR() __builtin_amdgcn_s_barrier()
#define WAIT_LGKM0()                                         \
  do {                                                       \
    asm volatile("s_waitcnt lgkmcnt(0)" ::: "memory");       \
    __builtin_amdgcn_sched_barrier(0);                       \
  } while (0)
#define WAIT_VM0()                                           \
  do {                                                       \
    asm volatile("s_waitcnt vmcnt(0)" ::: "memory");         \
  } while (0)

// ---------------------------------------------------------------------------
// 256x256-tile 8-wave GEMM, BK=64, dbuf 128KiB LDS, T2 swizzle, 8-phase.
// OUT-value = sum_e A[Arow][e]*B[Brow][e]  (A,B row-major, ld = DMODEL).
// MODE 0: OUT[Brow][Arow], Arow contiguous, j-packed 8B stores. grid (AT, BT).
// MODE 1: A=x (k rows), B=Y (q rows). E[k][q] = mask[k]?exp((s+v[k])/32):0
//         (nontemporal scalar stores, 16-lane-contiguous in q);
//         Zpart[cb][at2][q]. grid (64 = qt&7 + 8*kt, nb).
template <int MODE>
__global__ __launch_bounds__(512, 2)
void gemmT_kernel(const __hip_bfloat16* __restrict__ Aall,
                  const __hip_bfloat16* __restrict__ Ball,
                  __hip_bfloat16* __restrict__ OUT, int ldo,
                  const int* __restrict__ mask,
                  const float* __restrict__ vball,
                  float* __restrict__ Zpart, int b0) {
  __shared__ __align__(16) char smem[131072];
  const int t = threadIdx.x, lane = t & 63, wid = t >> 6;
  const int wm = wid >> 2, wn = wid & 3;
  const int g = lane >> 4, l15 = lane & 15, l7 = lane & 7;

  const __hip_bfloat16 *Ab, *Bb;
  int at2, bt2, cb = 0;
  if constexpr (MODE == 0) {
    at2 = blockIdx.x; bt2 = blockIdx.y;
    Ab = Aall + (size_t)at2 * 256 * DMODEL;
    Bb = Ball + (size_t)bt2 * 256 * DMODEL;
  } else {
    cb = blockIdx.y;
    bt2 = blockIdx.x & 7;       // q-tile; bx%8 -> XCD shares the Y panel
    at2 = blockIdx.x >> 3;      // k-tile
    Ab = Aall + ((size_t)(b0 + cb) * SEQ + at2 * 256) * DMODEL;
    Bb = Ball + ((size_t)(b0 + cb) * SEQ + bt2 * 256) * DMODEL;
  }

  char* bufA[2] = {smem, smem + 65536};
  char* bufB[2] = {smem + 32768, smem + 98304};

  const int srl = t >> 3;
  const int sc8 = (t & 7) ^ (srl & 7);          // pre-swizzled global col8
  const int pc8[2] = {g ^ l7, (4 + g) ^ l7};    // swizzled read col8

  auto stage_mat = [&](const __hip_bfloat16* gs, char* dst, int kt) {
#pragma unroll
    for (int h = 0; h < 2; ++h)
#pragma unroll
      for (int it = 0; it < 2; ++it)
        gload16(gs + (size_t)(h * 128 + it * 64 + srl) * DMODEL + kt * 64 + sc8 * 8,
                dst + h * 16384 + it * 8192 + wid * 1024);
  };

  f32x4 acc[8][4];
#pragma unroll
  for (int m = 0; m < 8; ++m)
#pragma unroll
    for (int n = 0; n < 4; ++n) acc[m][n] = (f32x4){0.f, 0.f, 0.f, 0.f};
  short8 afr[2][4], bfr[2][2][2];

#define LDA_Q(MH)                                                           \
  { _Pragma("unroll") for (int m = 0; m < 4; ++m) {                         \
      const int row = wm * 128 + ((MH) * 4 + m) * 16 + l15;                 \
      afr[0][m] = *(const short8*)(At + row * 128 + pc8[0] * 16);           \
      afr[1][m] = *(const short8*)(At + row * 128 + pc8[1] * 16);           \
    } }
#define LDB_Q(NH)                                                           \
  { _Pragma("unroll") for (int n = 0; n < 2; ++n) {                         \
      const int row = wn * 64 + ((NH) * 2 + n) * 16 + l15;                  \
      bfr[NH][0][n] = *(const short8*)(Bt + row * 128 + pc8[0] * 16);       \
      bfr[NH][1][n] = *(const short8*)(Bt + row * 128 + pc8[1] * 16);       \
    } }
#define MFMA_Q(MH, NH)                                                      \
  { __builtin_amdgcn_s_setprio(1);                                          \
    _Pragma("unroll") for (int kk = 0; kk < 2; ++kk)                        \
    _Pragma("unroll") for (int m = 0; m < 4; ++m)                           \
    _Pragma("unroll") for (int n = 0; n < 2; ++n)                           \
      acc[(MH)*4+m][(NH)*2+n] = __builtin_amdgcn_mfma_f32_16x16x32_bf16(    \
          afr[kk][m], bfr[NH][kk][n], acc[(MH)*4+m][(NH)*2+n], 0, 0, 0);    \
    __builtin_amdgcn_s_setprio(0); }

  stage_mat(Ab, bufA[0], 0);
  stage_mat(Bb, bufB[0], 0);
  WAIT_VM0();
  BAR();

  const char *At, *Bt;
#pragma unroll 1
  for (int i = 0; i < 8; ++i) {
    At = bufA[0]; Bt = bufB[0];
    LDA_Q(0) LDB_Q(0)
    stage_mat(Ab, bufA[1], 2 * i + 1);
    BAR(); WAIT_LGKM0(); MFMA_Q(0, 0) BAR();
    LDB_Q(1)
    stage_mat(Bb, bufB[1], 2 * i + 1);
    BAR(); WAIT_LGKM0(); MFMA_Q(0, 1) BAR();
    LDA_Q(1)
    BAR(); WAIT_LGKM0(); MFMA_Q(1, 0) BAR();
    MFMA_Q(1, 1)
    WAIT_VM0();
    BAR();
    At = bufA[1]; Bt = bufB[1];
    LDA_Q(0) LDB_Q(0)
    if (i < 7) stage_mat(Ab, bufA[0], 2 * i + 2);
    BAR(); WAIT_LGKM0(); MFMA_Q(0, 0) BAR();
    LDB_Q(1)
    if (i < 7) stage_mat(Bb, bufB[0], 2 * i + 2);
    BAR(); WAIT_LGKM0(); MFMA_Q(0, 1) BAR();
    LDA_Q(1)
    BAR(); WAIT_LGKM0(); MFMA_Q(1, 0) BAR();
    MFMA_Q(1, 1)
    WAIT_VM0();
    BAR();
  }
#undef LDA_Q
#undef LDB_Q
#undef MFMA_Q

  if constexpr (MODE == 0) {
    const size_t orow0 = (size_t)bt2 * 256 + wn * 64 + l15;
    const int ocol0 = at2 * 256 + wm * 128 + g * 4;
#pragma unroll
    for (int mi = 0; mi < 8; ++mi)
#pragma unroll
      for (int ni = 0; ni < 4; ++ni) {
        bf4 pk;
#pragma unroll
        for (int j = 0; j < 4; ++j) pk.h[j] = __float2bfloat16(acc[mi][ni][j]);
        *(bf4*)(OUT + (orow0 + ni * 16) * ldo + ocol0 + mi * 16) = pk;
      }
  } else {
    const int b = b0 + cb;
    float zc[4] = {0.f, 0.f, 0.f, 0.f};  // per-ni (q) partial Z
#pragma unroll
    for (int mi = 0; mi < 8; ++mi) {
      const int krow0 = at2 * 256 + wm * 128 + mi * 16 + g * 4;
      const int4 mk4 = *(const int4*)&mask[(size_t)b * SEQ + krow0];
      const float4 v4 = *(const float4*)&vball[(size_t)b * SEQ + krow0];
#pragma unroll
      for (int j = 0; j < 4; ++j) {
        const int km = (j == 0) ? mk4.x : (j == 1) ? mk4.y : (j == 2) ? mk4.z : mk4.w;
        const float vj = (j == 0) ? v4.x : (j == 1) ? v4.y : (j == 2) ? v4.z : v4.w;
        short* Erow = (short*)(OUT + ((size_t)cb * SEQ + krow0 + j) * (size_t)SEQ +
                               bt2 * 256 + wn * 64);
#pragma unroll
        for (int ni = 0; ni < 4; ++ni) {
          const float e = km ? __expf((acc[mi][ni][j] + vj) * 0.03125f) : 0.f;
          zc[ni] += e;
          __builtin_nontemporal_store(f2bfbits(e), Erow + ni * 16 + l15);
        }
      }
    }
#pragma unroll
    for (int ni = 0; ni < 4; ++ni) {
      float v = zc[ni];
      v += __shfl_xor(v, 16);
      v += __shfl_xor(v, 32);
      zc[ni] = v;
    }
    float* red = (float*)smem;  // [2][256]; tiles dead
    if (lane < 16) {
#pragma unroll
      for (int ni = 0; ni < 4; ++ni)
        red[wm * 256 + wn * 64 + ni * 16 + lane] = zc[ni];
    }
    __syncthreads();
    if (t < 256)
      Zpart[((size_t)cb * 8 + at2) * SEQ + bt2 * 256 + t] = red[t] + red[256 + t];
  }
}

// ---------------------------------------------------------------------------
// fp32 [DMODEL][DMODEL] -> bf16 transposed
__global__ void transpose_cvt_kernel(const float* __restrict__ in,
                                     __hip_bfloat16* __restrict__ outp) {
  __shared__ float tile[32][33];
  const int bx = blockIdx.x, by = blockIdx.y;
  const int tx = threadIdx.x & 31, ty = threadIdx.x >> 5;  // 32 x 8
#pragma unroll
  for (int r = 0; r < 32; r += 8)
    tile[ty + r][tx] = in[(size_t)(by * 32 + ty + r) * DMODEL + bx * 32 + tx];
  __syncthreads();
#pragma unroll
  for (int r = 0; r < 32; r += 8)
    outp[(size_t)(bx * 32 + ty + r) * DMODEL + by * 32 + tx] =
        __float2bfloat16(tile[tx][ty + r]);
}

// t2[d] = sum_e Wk[e][d]*bq[e]  (via WkT rows)
__global__ __launch_bounds__(256)
void prep_t2_kernel(const __hip_bfloat16* __restrict__ WkT,
                    const float* __restrict__ bq, float* __restrict__ t2) {
  const int wave = threadIdx.x >> 6, lane = threadIdx.x & 63;
  const int d = blockIdx.x * 4 + wave;
  const short8* kr = (const short8*)(WkT + (size_t)d * DMODEL);
  float a2 = 0.f;
#pragma unroll
  for (int h = 0; h < 2; ++h) {
    const short8 kv = kr[lane * 2 + h];
    const int e0 = lane * 16 + h * 8;
#pragma unroll
    for (int i = 0; i < 8; ++i) a2 += bf2f(kv[i]) * bq[e0 + i];
  }
  a2 += __shfl_down(a2, 32); a2 += __shfl_down(a2, 16); a2 += __shfl_down(a2, 8);
  a2 += __shfl_down(a2, 4);  a2 += __shfl_down(a2, 2);  a2 += __shfl_down(a2, 1);
  if (lane == 0) t2[d] = a2;
}

// fused: x fp32 -> x_bf (all batches) + vb[row] = x[row].t2
__global__ __launch_bounds__(256)
void cvtv_kernel(const float* __restrict__ x, const float* __restrict__ t2,
                 __hip_bfloat16* __restrict__ x_bf, float* __restrict__ vb) {
  const int wave = threadIdx.x >> 6, lane = threadIdx.x & 63;
  const size_t row = (size_t)blockIdx.x * 4 + wave;
  const float* xr = x + row * DMODEL;
  float a2 = 0.f;
#pragma unroll
  for (int p = 0; p < 4; ++p) {
    const int d = p * 256 + lane * 4;
    const float4 xv = *(const float4*)(xr + d);
    const float4 tv = *(const float4*)(t2 + d);
    a2 += xv.x * tv.x + xv.y * tv.y + xv.z * tv.z + xv.w * tv.w;
    bf4 pk;
    pk.h[0] = __float2bfloat16(xv.x); pk.h[1] = __float2bfloat16(xv.y);
    pk.h[2] = __float2bfloat16(xv.z); pk.h[3] = __float2bfloat16(xv.w);
    *(bf4*)(x_bf + row * DMODEL + d) = pk;
  }
  a2 += __shfl_down(a2, 32); a2 += __shfl_down(a2, 16); a2 += __shfl_down(a2, 8);
  a2 += __shfl_down(a2, 4);  a2 += __shfl_down(a2, 2);  a2 += __shfl_down(a2, 1);
  if (lane == 0) vb[row] = a2;
}

// rZ[cb][q] = 1 / sum_{at2<8} Zpart[cb][at2][q]  (0 if empty)
__global__ void zinv_kernel(const float* __restrict__ Zpart,
                            float* __restrict__ rZ, int n) {
  const int idx = blockIdx.x * 256 + threadIdx.x;
  if (idx >= n) return;
  const int cb = idx >> 11, q = idx & (SEQ - 1);
  float z = 0.f;
#pragma unroll
  for (int kt = 0; kt < 8; ++kt)
    z += Zpart[((size_t)cb * 8 + kt) * SEQ + q];
  rZ[(size_t)cb * SEQ + q] = (z > 0.f) ? (1.f / z) : 0.f;
}

// passB: w[k] = sum_q E[k][q] * rZ[q]  (rZ slice in regs, coalesced E rows)
__global__ __launch_bounds__(256)
void passB_kernel(const __hip_bfloat16* __restrict__ E,
                  const float* __restrict__ rZ,
                  float* __restrict__ wout) {
  const int t = threadIdx.x, lane = t & 63, wave = t >> 6;
  const int cb = blockIdx.y;
  float4 rzv[4][2];
#pragma unroll
  for (int it = 0; it < 4; ++it) {
    const float4* p = (const float4*)(rZ + (size_t)cb * SEQ + it * 512 + lane * 8);
    rzv[it][0] = p[0];
    rzv[it][1] = p[1];
  }
  const int kbase = blockIdx.x * 16 + wave * 4;
#pragma unroll
  for (int r = 0; r < 4; ++r) {
    const int k = kbase + r;
    const short8* Ep = (const short8*)(E + ((size_t)cb * SEQ + k) * SEQ);
    float s = 0.f;
#pragma unroll
    for (int it = 0; it < 4; ++it) {
      const short8 v = Ep[it * 64 + lane];
      const float* rz = (const float*)&rzv[it][0];
#pragma unroll
      for (int e = 0; e < 8; ++e) s += bf2f(v[e]) * rz[e];
    }
    s += __shfl_down(s, 32); s += __shfl_down(s, 16); s += __shfl_down(s, 8);
    s += __shfl_down(s, 4);  s += __shfl_down(s, 2);  s += __shfl_down(s, 1);
    if (lane == 0) wout[(size_t)cb * SEQ + k] = s;
  }
}

// sumw_all[b] = sum_k w[k]
__global__ void sumw_kernel(const float* __restrict__ w,
                            float* __restrict__ sumw_all, int b0) {
  __shared__ float sred[4];
  const int t = threadIdx.x, lane = t & 63, wave = t >> 6;
  const int cb = blockIdx.x;
  float v = 0.f;
  for (int k = t; k < SEQ; k += 256) v += w[(size_t)cb * SEQ + k];
  v += __shfl_down(v, 32); v += __shfl_down(v, 16); v += __shfl_down(v, 8);
  v += __shfl_down(v, 4);  v += __shfl_down(v, 2);  v += __shfl_down(v, 1);
  if (lane == 0) sred[wave] = v;
  __syncthreads();
  if (t == 0) sumw_all[b0 + cb] = sred[0] + sred[1] + sred[2] + sred[3];
}

// wxp[kq][b][d] = sum_{k in chunk kq} w[k] * x_bf[b][k][d]
__global__ void wxpart_kernel(const __hip_bfloat16* __restrict__ x_bf,
                              const float* __restrict__ w,
                              float* __restrict__ wxp, int b0) {
  const int dt = blockIdx.x, cb = blockIdx.y, kq = blockIdx.z;
  const int b = b0 + cb;
  const int dp = dt * 256 + threadIdx.x;
  const __hip_bfloat16* xb =
      x_bf + ((size_t)b * SEQ + (size_t)kq * (SEQ / KSPLIT)) * DMODEL;
  const float* wb = w + (size_t)cb * SEQ + (size_t)kq * (SEQ / KSPLIT);
  float a0 = 0.f, a1 = 0.f;
#pragma unroll 4
  for (int k = 0; k < SEQ / KSPLIT; ++k) {
    const float wk = wb[k];
    const uint32_t pv = *(const uint32_t*)(xb + (size_t)k * DMODEL + dp * 2);
    a0 += wk * bf2f((short)(pv & 0xffff));
    a1 += wk * bf2f((short)(pv >> 16));
  }
  float2* o = (float2*)&wxp[((size_t)kq * NBATCH + b) * DMODEL + dp * 2];
  *o = make_float2(a0, a1);
}

// out[b][e] = ( sum_d (sum_kq wxp[kq][b][d]) * Wv[e][d] + sumw[b]*bv[e] ) / SEQ
__global__ void final_kernel(const float* __restrict__ wxp,
                             const float* __restrict__ sumw_all,
                             const float* __restrict__ Wv,
                             const float* __restrict__ bv,
                             float* __restrict__ out) {
  const int b = blockIdx.y, eg = blockIdx.x;
  const int wave = threadIdx.x >> 6, lane = threadIdx.x & 63;
  const int e = eg * 4 + wave;
  float acc = 0.f;
  for (int d = lane; d < DMODEL; d += 64) {
    float wx = 0.f;
#pragma unroll
    for (int kq = 0; kq < KSPLIT; ++kq)
      wx += wxp[((size_t)kq * NBATCH + b) * DMODEL + d];
    acc += wx * Wv[(size_t)e * DMODEL + d];
  }
  acc += __shfl_down(acc, 32); acc += __shfl_down(acc, 16);
  acc += __shfl_down(acc, 8);  acc += __shfl_down(acc, 4);
  acc += __shfl_down(acc, 2);  acc += __shfl_down(acc, 1);
  if (lane == 0)
    out[(size_t)b * DMODEL + e] =
        (acc + sumw_all[b] * bv[e]) * (1.f / (float)SEQ);
}

// ---------------------------------------------------------------------------
extern "C" void kernel_launch(void* const* d_in, const int* in_sizes, int n_in,
                              void* d_out, int out_size, void* d_ws, size_t ws_size,
                              hipStream_t stream) {
  const float* x  = (const float*)d_in[0];
  const int* mask = (const int*)d_in[1];
  const float* Wq = (const float*)d_in[2];
  const float* bq = (const float*)d_in[3];
  const float* Wk = (const float*)d_in[4];
  const float* bk = (const float*)d_in[5];
  const float* Wv = (const float*)d_in[6];
  const float* bv = (const float*)d_in[7];
  float* out = (float*)d_out;
  (void)bk;

  char* ws = (char*)d_ws;
  size_t off = 0;
  auto alloc = [&](size_t bytes) -> void* {
    void* p = ws + off;
    off += (bytes + 255) & ~(size_t)255;
    return p;
  };
  // ---- persistent ----
  __hip_bfloat16* Mt_bf  = (__hip_bfloat16*)alloc((size_t)DMODEL * DMODEL * 2);
  __hip_bfloat16* WqT_bf = (__hip_bfloat16*)alloc((size_t)DMODEL * DMODEL * 2);
  __hip_bfloat16* WkT_bf = (__hip_bfloat16*)alloc((size_t)DMODEL * DMODEL * 2);
  float* wxp      = (float*)alloc((size_t)KSPLIT * NBATCH * DMODEL * 4);
  float* sumw_all = (float*)alloc((size_t)NBATCH * 4);
  float* t2       = (float*)alloc((size_t)DMODEL * 4);
  __hip_bfloat16* x_bf = (__hip_bfloat16*)alloc((size_t)NBATCH * SEQ * DMODEL * 2);
  __hip_bfloat16* Yb   = (__hip_bfloat16*)alloc((size_t)NBATCH * SEQ * DMODEL * 2);
  float* vb = (float*)alloc((size_t)NBATCH * SEQ * 4);
  const size_t fixed = off;

  // ---- per-chunk (E + small per-batch) ----
  const size_t per_batch = (size_t)SEQ * SEQ * 2       // E
                         + (size_t)8 * SEQ * 4         // Zpart
                         + (size_t)2 * SEQ * 4 + 8 * 256;
  long avail = (long)ws_size - (long)fixed;
  int NB = (int)(avail / (long)per_batch);
  if (NB < 1) NB = 1;
  if (NB > NBATCH) NB = NBATCH;
  while (NBATCH % NB) --NB;   // NB in {1,2,4,8,16}
  __hip_bfloat16* Ebuf = (__hip_bfloat16*)alloc((size_t)NB * SEQ * SEQ * 2);
  float* Zpart = (float*)alloc((size_t)NB * 8 * SEQ * 4);
  float* rZ    = (float*)alloc((size_t)NB * SEQ * 4);
  float* wbuf  = (float*)alloc((size_t)NB * SEQ * 4);

  // ---- prep ----
  transpose_cvt_kernel<<<dim3(32, 32), dim3(256), 0, stream>>>(Wq, WqT_bf);
  transpose_cvt_kernel<<<dim3(32, 32), dim3(256), 0, stream>>>(Wk, WkT_bf);
  // Mt[d'][d] = sum_e WkT[d'][e]*WqT[d][e]
  gemmT_kernel<0><<<dim3(4, 4), dim3(512), 0, stream>>>(
      WqT_bf, WkT_bf, Mt_bf, DMODEL, nullptr, nullptr, nullptr, 0);
  prep_t2_kernel<<<dim3(256), dim3(256), 0, stream>>>(WkT_bf, bq, t2);
  cvtv_kernel<<<dim3(NBATCH * SEQ / 4), dim3(256), 0, stream>>>(x, t2, x_bf, vb);
  // Y[q][d'] = sum_d x[q][d]*Mt[d'][d]
  gemmT_kernel<0><<<dim3(4, NBATCH * 8), dim3(512), 0, stream>>>(
      Mt_bf, x_bf, Yb, DMODEL, nullptr, nullptr, nullptr, 0);

  for (int b0 = 0; b0 < NBATCH; b0 += NB) {
    const int nb = NB;
    // E[k][q] (nt stores) + Zpart
    gemmT_kernel<1><<<dim3(64, nb), dim3(512), 0, stream>>>(
        x_bf, Yb, Ebuf, SEQ, mask, vb, Zpart, b0);
    zinv_kernel<<<dim3((nb * SEQ + 255) / 256), dim3(256), 0, stream>>>(
        Zpart, rZ, nb * SEQ);
    passB_kernel<<<dim3(SEQ / 16, nb), dim3(256), 0, stream>>>(Ebuf, rZ, wbuf);
    sumw_kernel<<<dim3(nb), dim3(256), 0, stream>>>(wbuf, sumw_all, b0);
    wxpart_kernel<<<dim3(DMODEL / 512, nb, KSPLIT), dim3(256), 0, stream>>>(
        x_bf, wbuf, wxp, b0);
  }
  final_kernel<<<dim3(DMODEL / 4, NBATCH), dim3(256), 0, stream>>>(
      wxp, sumw_all, Wv, bv, out);
}

// Round 8
// 390.947 us; speedup vs baseline: 1.3080x; 1.0009x over previous
//
#include <hip/hip_runtime.h>
#include <hip/hip_bf16.h>
#include <stdint.h>

#define NBATCH 16
#define SEQ    2048
#define DMODEL 1024
#define KSPLIT 8

typedef __attribute__((ext_vector_type(8))) short short8;   // 8 bf16 = 4 VGPRs
typedef __attribute__((ext_vector_type(4))) float f32x4;

struct __align__(8) bf4 { __hip_bfloat16 h[4]; };

__device__ __forceinline__ float bf2f(short s) {
  union { uint32_t u; float f; } c;
  c.u = ((uint32_t)(uint16_t)s) << 16;
  return c.f;
}

// async global -> LDS, 16B/lane. LDS dest = wave-uniform base + lane*16.
__device__ __forceinline__ void gload16(const void* g, void* l) {
  __builtin_amdgcn_global_load_lds(
      (const __attribute__((address_space(1))) void*)g,
      (__attribute__((address_space(3))) void*)l, 16, 0, 0);
}

#define BAR() __builtin_amdgcn_s_barrier()
#define WAIT_LGKM0()                                         \
  do {                                                       \
    asm volatile("s_waitcnt lgkmcnt(0)" ::: "memory");       \
    __builtin_amdgcn_sched_barrier(0);                       \
  } while (0)
#define WAIT_VM0()                                           \
  do {                                                       \
    asm volatile("s_waitcnt vmcnt(0)" ::: "memory");         \
  } while (0)
#define WAIT_VM8()                                           \
  do {                                                       \
    asm volatile("s_waitcnt vmcnt(8)" ::: "memory");         \
  } while (0)

// ---------------------------------------------------------------------------
// 256x256-tile 8-wave GEMM, BK=64, dbuf 128KiB LDS, T2 swizzle, 8-phase,
// counted-vmcnt deep pipeline (tile t+2 staged at tile t ph4; boundary waits
// vmcnt(8), never 0, until the epilogue tiles).
// OUT-value = sum_e A[Arow][e]*B[Brow][e]  (A,B row-major, ld = DMODEL).
// MODE 0: OUT[Brow][Arow], Arow contiguous, j-packed 8B stores. grid (AT, BT).
// MODE 1: A=x (k rows), B=Y (q rows). E[k][q] = mask[k]?exp((s+v[k])/32):0
//         (scalar bf16 stores, 16-lane-contiguous in q); Zpart[cb][at2][q].
//         grid (64 = qt&7 + 8*kt, nb).
template <int MODE>
__global__ __launch_bounds__(512, 2)
void gemmT_kernel(const __hip_bfloat16* __restrict__ Aall,
                  const __hip_bfloat16* __restrict__ Ball,
                  __hip_bfloat16* __restrict__ OUT, int ldo,
                  const int* __restrict__ mask,
                  const float* __restrict__ vball,
                  float* __restrict__ Zpart, int b0) {
  __shared__ __align__(16) char smem[131072];
  const int t = threadIdx.x, lane = t & 63, wid = t >> 6;
  const int wm = wid >> 2, wn = wid & 3;
  const int g = lane >> 4, l15 = lane & 15, l7 = lane & 7;

  const __hip_bfloat16 *Ab, *Bb;
  int at2, bt2, cb = 0;
  if constexpr (MODE == 0) {
    at2 = blockIdx.x; bt2 = blockIdx.y;
    Ab = Aall + (size_t)at2 * 256 * DMODEL;
    Bb = Ball + (size_t)bt2 * 256 * DMODEL;
  } else {
    cb = blockIdx.y;
    bt2 = blockIdx.x & 7;       // q-tile; bx%8 -> XCD shares the Y panel
    at2 = blockIdx.x >> 3;      // k-tile
    Ab = Aall + ((size_t)(b0 + cb) * SEQ + at2 * 256) * DMODEL;
    Bb = Ball + ((size_t)(b0 + cb) * SEQ + bt2 * 256) * DMODEL;
  }

  // buffer pointers computed arithmetically (runtime LDS pointer math is ok;
  // a static-initialized array of LDS pointers is NOT — addrspacecast error)
  auto bufA = [&](int p) -> char* { return smem + (p << 16); };
  auto bufB = [&](int p) -> char* { return smem + 32768 + (p << 16); };

  const int srl = t >> 3;
  const int sc8 = (t & 7) ^ (srl & 7);          // pre-swizzled global col8
  const int pc8[2] = {g ^ l7, (4 + g) ^ l7};    // swizzled read col8

  auto stage_mat = [&](const __hip_bfloat16* gs, char* dst, int kt) {
#pragma unroll
    for (int h = 0; h < 2; ++h)
#pragma unroll
      for (int it = 0; it < 2; ++it)
        gload16(gs + (size_t)(h * 128 + it * 64 + srl) * DMODEL + kt * 64 + sc8 * 8,
                dst + h * 16384 + it * 8192 + wid * 1024);
  };

  f32x4 acc[8][4];
#pragma unroll
  for (int m = 0; m < 8; ++m)
#pragma unroll
    for (int n = 0; n < 4; ++n) acc[m][n] = (f32x4){0.f, 0.f, 0.f, 0.f};
  short8 afr[2][4], bfr[2][2][2];

#define LDA_Q(MH)                                                           \
  { _Pragma("unroll") for (int m = 0; m < 4; ++m) {                         \
      const int row = wm * 128 + ((MH) * 4 + m) * 16 + l15;                 \
      afr[0][m] = *(const short8*)(At + row * 128 + pc8[0] * 16);           \
      afr[1][m] = *(const short8*)(At + row * 128 + pc8[1] * 16);           \
    } }
#define LDB_Q(NH)                                                           \
  { _Pragma("unroll") for (int n = 0; n < 2; ++n) {                         \
      const int row = wn * 64 + ((NH) * 2 + n) * 16 + l15;                  \
      bfr[NH][0][n] = *(const short8*)(Bt + row * 128 + pc8[0] * 16);       \
      bfr[NH][1][n] = *(const short8*)(Bt + row * 128 + pc8[1] * 16);       \
    } }
#define MFMA_Q(MH, NH)                                                      \
  { __builtin_amdgcn_s_setprio(1);                                          \
    _Pragma("unroll") for (int kk = 0; kk < 2; ++kk)                        \
    _Pragma("unroll") for (int m = 0; m < 4; ++m)                           \
    _Pragma("unroll") for (int n = 0; n < 2; ++n)                           \
      acc[(MH)*4+m][(NH)*2+n] = __builtin_amdgcn_mfma_f32_16x16x32_bf16(    \
          afr[kk][m], bfr[NH][kk][n], acc[(MH)*4+m][(NH)*2+n], 0, 0, 0);    \
    __builtin_amdgcn_s_setprio(0); }

  // prologue: tile 0 -> buf0
  stage_mat(Ab, bufA(0), 0);
  stage_mat(Bb, bufB(0), 0);
  WAIT_VM0();
  BAR();

#pragma unroll 1
  for (int i = 0; i < 16; ++i) {
    const int p = i & 1;
    const char* At = bufA(p);
    const char* Bt = bufB(p);
    // ph1: LDA half 0, LDB half 0
    LDA_Q(0) LDB_Q(0)
    if (i == 0) stage_mat(Ab, bufA(1), 1);
    BAR(); WAIT_LGKM0(); MFMA_Q(0, 0) BAR();
    // ph2: LDB half 1 (bufB(p) fully read after this phase's lgkm)
    LDB_Q(1)
    if (i == 0) stage_mat(Bb, bufB(1), 1);
    BAR(); WAIT_LGKM0(); MFMA_Q(0, 1) BAR();
    // ph3: LDA half 1 (bufA(p) fully read after this phase's lgkm)
    LDA_Q(1)
    BAR(); WAIT_LGKM0(); MFMA_Q(1, 0) BAR();
    // ph4: stage tile i+2 into buf(p) (both halves provably free: all waves
    // passed ph2/ph3 closing barriers AFTER draining their reads).
    if (i < 14) { stage_mat(Ab, bufA(p), i + 2); stage_mat(Bb, bufB(p), i + 2); }
    MFMA_Q(1, 1)
    // drain tile i+1's 8 loads only; keep tile i+2's 8 in flight.
    if (i < 14) { WAIT_VM8(); } else { WAIT_VM0(); }
    BAR();
  }
#undef LDA_Q
#undef LDB_Q
#undef MFMA_Q

  if constexpr (MODE == 0) {
    const size_t orow0 = (size_t)bt2 * 256 + wn * 64 + l15;
    const int ocol0 = at2 * 256 + wm * 128 + g * 4;
#pragma unroll
    for (int mi = 0; mi < 8; ++mi)
#pragma unroll
      for (int ni = 0; ni < 4; ++ni) {
        bf4 pk;
#pragma unroll
        for (int j = 0; j < 4; ++j) pk.h[j] = __float2bfloat16(acc[mi][ni][j]);
        *(bf4*)(OUT + (orow0 + ni * 16) * ldo + ocol0 + mi * 16) = pk;
      }
  } else {
    const int b = b0 + cb;
    float zc[4] = {0.f, 0.f, 0.f, 0.f};  // per-ni (q) partial Z
#pragma unroll
    for (int mi = 0; mi < 8; ++mi) {
      const int krow0 = at2 * 256 + wm * 128 + mi * 16 + g * 4;
      const int4 mk4 = *(const int4*)&mask[(size_t)b * SEQ + krow0];
      const float4 v4 = *(const float4*)&vball[(size_t)b * SEQ + krow0];
#pragma unroll
      for (int j = 0; j < 4; ++j) {
        const int km = (j == 0) ? mk4.x : (j == 1) ? mk4.y : (j == 2) ? mk4.z : mk4.w;
        const float vj = (j == 0) ? v4.x : (j == 1) ? v4.y : (j == 2) ? v4.z : v4.w;
        __hip_bfloat16* Erow =
            OUT + ((size_t)cb * SEQ + krow0 + j) * (size_t)SEQ + bt2 * 256 + wn * 64;
#pragma unroll
        for (int ni = 0; ni < 4; ++ni) {
          const float e = km ? __expf((acc[mi][ni][j] + vj) * 0.03125f) : 0.f;
          zc[ni] += e;
          Erow[ni * 16 + l15] = __float2bfloat16(e);
        }
      }
    }
#pragma unroll
    for (int ni = 0; ni < 4; ++ni) {
      float v = zc[ni];
      v += __shfl_xor(v, 16);
      v += __shfl_xor(v, 32);
      zc[ni] = v;
    }
    float* red = (float*)smem;  // [2][256]; tiles dead
    if (lane < 16) {
#pragma unroll
      for (int ni = 0; ni < 4; ++ni)
        red[wm * 256 + wn * 64 + ni * 16 + lane] = zc[ni];
    }
    __syncthreads();
    if (t < 256)
      Zpart[((size_t)cb * 8 + at2) * SEQ + bt2 * 256 + t] = red[t] + red[256 + t];
  }
}

// ---------------------------------------------------------------------------
// fp32 [DMODEL][DMODEL] -> bf16 transposed
__global__ void transpose_cvt_kernel(const float* __restrict__ in,
                                     __hip_bfloat16* __restrict__ outp) {
  __shared__ float tile[32][33];
  const int bx = blockIdx.x, by = blockIdx.y;
  const int tx = threadIdx.x & 31, ty = threadIdx.x >> 5;  // 32 x 8
#pragma unroll
  for (int r = 0; r < 32; r += 8)
    tile[ty + r][tx] = in[(size_t)(by * 32 + ty + r) * DMODEL + bx * 32 + tx];
  __syncthreads();
#pragma unroll
  for (int r = 0; r < 32; r += 8)
    outp[(size_t)(bx * 32 + ty + r) * DMODEL + by * 32 + tx] =
        __float2bfloat16(tile[tx][ty + r]);
}

// t2[d] = sum_e Wk[e][d]*bq[e]  (via WkT rows)
__global__ __launch_bounds__(256)
void prep_t2_kernel(const __hip_bfloat16* __restrict__ WkT,
                    const float* __restrict__ bq, float* __restrict__ t2) {
  const int wave = threadIdx.x >> 6, lane = threadIdx.x & 63;
  const int d = blockIdx.x * 4 + wave;
  const short8* kr = (const short8*)(WkT + (size_t)d * DMODEL);
  float a2 = 0.f;
#pragma unroll
  for (int h = 0; h < 2; ++h) {
    const short8 kv = kr[lane * 2 + h];
    const int e0 = lane * 16 + h * 8;
#pragma unroll
    for (int i = 0; i < 8; ++i) a2 += bf2f(kv[i]) * bq[e0 + i];
  }
  a2 += __shfl_down(a2, 32); a2 += __shfl_down(a2, 16); a2 += __shfl_down(a2, 8);
  a2 += __shfl_down(a2, 4);  a2 += __shfl_down(a2, 2);  a2 += __shfl_down(a2, 1);
  if (lane == 0) t2[d] = a2;
}

// fused: x fp32 -> x_bf (all batches) + vb[row] = x[row].t2
__global__ __launch_bounds__(256)
void cvtv_kernel(const float* __restrict__ x, const float* __restrict__ t2,
                 __hip_bfloat16* __restrict__ x_bf, float* __restrict__ vb) {
  const int wave = threadIdx.x >> 6, lane = threadIdx.x & 63;
  const size_t row = (size_t)blockIdx.x * 4 + wave;
  const float* xr = x + row * DMODEL;
  float a2 = 0.f;
#pragma unroll
  for (int p = 0; p < 4; ++p) {
    const int d = p * 256 + lane * 4;
    const float4 xv = *(const float4*)(xr + d);
    const float4 tv = *(const float4*)(t2 + d);
    a2 += xv.x * tv.x + xv.y * tv.y + xv.z * tv.z + xv.w * tv.w;
    bf4 pk;
    pk.h[0] = __float2bfloat16(xv.x); pk.h[1] = __float2bfloat16(xv.y);
    pk.h[2] = __float2bfloat16(xv.z); pk.h[3] = __float2bfloat16(xv.w);
    *(bf4*)(x_bf + row * DMODEL + d) = pk;
  }
  a2 += __shfl_down(a2, 32); a2 += __shfl_down(a2, 16); a2 += __shfl_down(a2, 8);
  a2 += __shfl_down(a2, 4);  a2 += __shfl_down(a2, 2);  a2 += __shfl_down(a2, 1);
  if (lane == 0) vb[row] = a2;
}

// rZ[cb][q] = 1 / sum_{at2<8} Zpart[cb][at2][q]  (0 if empty)
__global__ void zinv_kernel(const float* __restrict__ Zpart,
                            float* __restrict__ rZ, int n) {
  const int idx = blockIdx.x * 256 + threadIdx.x;
  if (idx >= n) return;
  const int cb = idx >> 11, q = idx & (SEQ - 1);
  float z = 0.f;
#pragma unroll
  for (int kt = 0; kt < 8; ++kt)
    z += Zpart[((size_t)cb * 8 + kt) * SEQ + q];
  rZ[(size_t)cb * SEQ + q] = (z > 0.f) ? (1.f / z) : 0.f;
}

// passB: w[k] = sum_q E[k][q] * rZ[q]  (rZ slice in regs, coalesced E rows)
__global__ __launch_bounds__(256)
void passB_kernel(const __hip_bfloat16* __restrict__ E,
                  const float* __restrict__ rZ,
                  float* __restrict__ wout) {
  const int t = threadIdx.x, lane = t & 63, wave = t >> 6;
  const int cb = blockIdx.y;
  float4 rzv[4][2];
#pragma unroll
  for (int it = 0; it < 4; ++it) {
    const float4* p = (const float4*)(rZ + (size_t)cb * SEQ + it * 512 + lane * 8);
    rzv[it][0] = p[0];
    rzv[it][1] = p[1];
  }
  const int kbase = blockIdx.x * 16 + wave * 4;
#pragma unroll
  for (int r = 0; r < 4; ++r) {
    const int k = kbase + r;
    const short8* Ep = (const short8*)(E + ((size_t)cb * SEQ + k) * SEQ);
    float s = 0.f;
#pragma unroll
    for (int it = 0; it < 4; ++it) {
      const short8 v = Ep[it * 64 + lane];
      const float* rz = (const float*)&rzv[it][0];
#pragma unroll
      for (int e = 0; e < 8; ++e) s += bf2f(v[e]) * rz[e];
    }
    s += __shfl_down(s, 32); s += __shfl_down(s, 16); s += __shfl_down(s, 8);
    s += __shfl_down(s, 4);  s += __shfl_down(s, 2);  s += __shfl_down(s, 1);
    if (lane == 0) wout[(size_t)cb * SEQ + k] = s;
  }
}

// sumw_all[b] = sum_k w[k]
__global__ void sumw_kernel(const float* __restrict__ w,
                            float* __restrict__ sumw_all, int b0) {
  __shared__ float sred[4];
  const int t = threadIdx.x, lane = t & 63, wave = t >> 6;
  const int cb = blockIdx.x;
  float v = 0.f;
  for (int k = t; k < SEQ; k += 256) v += w[(size_t)cb * SEQ + k];
  v += __shfl_down(v, 32); v += __shfl_down(v, 16); v += __shfl_down(v, 8);
  v += __shfl_down(v, 4);  v += __shfl_down(v, 2);  v += __shfl_down(v, 1);
  if (lane == 0) sred[wave] = v;
  __syncthreads();
  if (t == 0) sumw_all[b0 + cb] = sred[0] + sred[1] + sred[2] + sred[3];
}

// wxp[kq][b][d] = sum_{k in chunk kq} w[k] * x_bf[b][k][d]
__global__ void wxpart_kernel(const __hip_bfloat16* __restrict__ x_bf,
                              const float* __restrict__ w,
                              float* __restrict__ wxp, int b0) {
  const int dt = blockIdx.x, cb = blockIdx.y, kq = blockIdx.z;
  const int b = b0 + cb;
  const int dp = dt * 256 + threadIdx.x;
  const __hip_bfloat16* xb =
      x_bf + ((size_t)b * SEQ + (size_t)kq * (SEQ / KSPLIT)) * DMODEL;
  const float* wb = w + (size_t)cb * SEQ + (size_t)kq * (SEQ / KSPLIT);
  float a0 = 0.f, a1 = 0.f;
#pragma unroll 4
  for (int k = 0; k < SEQ / KSPLIT; ++k) {
    const float wk = wb[k];
    const uint32_t pv = *(const uint32_t*)(xb + (size_t)k * DMODEL + dp * 2);
    a0 += wk * bf2f((short)(pv & 0xffff));
    a1 += wk * bf2f((short)(pv >> 16));
  }
  float2* o = (float2*)&wxp[((size_t)kq * NBATCH + b) * DMODEL + dp * 2];
  *o = make_float2(a0, a1);
}

// out[b][e] = ( sum_d (sum_kq wxp[kq][b][d]) * Wv[e][d] + sumw[b]*bv[e] ) / SEQ
__global__ void final_kernel(const float* __restrict__ wxp,
                             const float* __restrict__ sumw_all,
                             const float* __restrict__ Wv,
                             const float* __restrict__ bv,
                             float* __restrict__ out) {
  const int b = blockIdx.y, eg = blockIdx.x;
  const int wave = threadIdx.x >> 6, lane = threadIdx.x & 63;
  const int e = eg * 4 + wave;
  float acc = 0.f;
  for (int d = lane; d < DMODEL; d += 64) {
    float wx = 0.f;
#pragma unroll
    for (int kq = 0; kq < KSPLIT; ++kq)
      wx += wxp[((size_t)kq * NBATCH + b) * DMODEL + d];
    acc += wx * Wv[(size_t)e * DMODEL + d];
  }
  acc += __shfl_down(acc, 32); acc += __shfl_down(acc, 16);
  acc += __shfl_down(acc, 8);  acc += __shfl_down(acc, 4);
  acc += __shfl_down(acc, 2);  acc += __shfl_down(acc, 1);
  if (lane == 0)
    out[(size_t)b * DMODEL + e] =
        (acc + sumw_all[b] * bv[e]) * (1.f / (float)SEQ);
}

// ---------------------------------------------------------------------------
extern "C" void kernel_launch(void* const* d_in, const int* in_sizes, int n_in,
                              void* d_out, int out_size, void* d_ws, size_t ws_size,
                              hipStream_t stream) {
  const float* x  = (const float*)d_in[0];
  const int* mask = (const int*)d_in[1];
  const float* Wq = (const float*)d_in[2];
  const float* bq = (const float*)d_in[3];
  const float* Wk = (const float*)d_in[4];
  const float* bk = (const float*)d_in[5];
  const float* Wv = (const float*)d_in[6];
  const float* bv = (const float*)d_in[7];
  float* out = (float*)d_out;
  (void)bk;

  char* ws = (char*)d_ws;
  size_t off = 0;
  auto alloc = [&](size_t bytes) -> void* {
    void* p = ws + off;
    off += (bytes + 255) & ~(size_t)255;
    return p;
  };
  // ---- persistent ----
  __hip_bfloat16* Mt_bf  = (__hip_bfloat16*)alloc((size_t)DMODEL * DMODEL * 2);
  __hip_bfloat16* WqT_bf = (__hip_bfloat16*)alloc((size_t)DMODEL * DMODEL * 2);
  __hip_bfloat16* WkT_bf = (__hip_bfloat16*)alloc((size_t)DMODEL * DMODEL * 2);
  float* wxp      = (float*)alloc((size_t)KSPLIT * NBATCH * DMODEL * 4);
  float* sumw_all = (float*)alloc((size_t)NBATCH * 4);
  float* t2       = (float*)alloc((size_t)DMODEL * 4);
  __hip_bfloat16* x_bf = (__hip_bfloat16*)alloc((size_t)NBATCH * SEQ * DMODEL * 2);
  __hip_bfloat16* Yb   = (__hip_bfloat16*)alloc((size_t)NBATCH * SEQ * DMODEL * 2);
  float* vb = (float*)alloc((size_t)NBATCH * SEQ * 4);
  const size_t fixed = off;

  // ---- per-chunk (E + small per-batch) ----
  const size_t per_batch = (size_t)SEQ * SEQ * 2       // E
                         + (size_t)8 * SEQ * 4         // Zpart
                         + (size_t)2 * SEQ * 4 + 8 * 256;
  long avail = (long)ws_size - (long)fixed;
  int NB = (int)(avail / (long)per_batch);
  if (NB < 1) NB = 1;
  if (NB > NBATCH) NB = NBATCH;
  while (NBATCH % NB) --NB;   // NB in {1,2,4,8,16}
  __hip_bfloat16* Ebuf = (__hip_bfloat16*)alloc((size_t)NB * SEQ * SEQ * 2);
  float* Zpart = (float*)alloc((size_t)NB * 8 * SEQ * 4);
  float* rZ    = (float*)alloc((size_t)NB * SEQ * 4);
  float* wbuf  = (float*)alloc((size_t)NB * SEQ * 4);

  // ---- prep ----
  transpose_cvt_kernel<<<dim3(32, 32), dim3(256), 0, stream>>>(Wq, WqT_bf);
  transpose_cvt_kernel<<<dim3(32, 32), dim3(256), 0, stream>>>(Wk, WkT_bf);
  // Mt[d'][d] = sum_e WkT[d'][e]*WqT[d][e]
  gemmT_kernel<0><<<dim3(4, 4), dim3(512), 0, stream>>>(
      WqT_bf, WkT_bf, Mt_bf, DMODEL, nullptr, nullptr, nullptr, 0);
  prep_t2_kernel<<<dim3(256), dim3(256), 0, stream>>>(WkT_bf, bq, t2);
  cvtv_kernel<<<dim3(NBATCH * SEQ / 4), dim3(256), 0, stream>>>(x, t2, x_bf, vb);
  // Y[q][d'] = sum_d x[q][d]*Mt[d'][d]
  gemmT_kernel<0><<<dim3(4, NBATCH * 8), dim3(512), 0, stream>>>(
      Mt_bf, x_bf, Yb, DMODEL, nullptr, nullptr, nullptr, 0);

  for (int b0 = 0; b0 < NBATCH; b0 += NB) {
    const int nb = NB;
    // E[k][q] + Zpart
    gemmT_kernel<1><<<dim3(64, nb), dim3(512), 0, stream>>>(
        x_bf, Yb, Ebuf, SEQ, mask, vb, Zpart, b0);
    zinv_kernel<<<dim3((nb * SEQ + 255) / 256), dim3(256), 0, stream>>>(
        Zpart, rZ, nb * SEQ);
    passB_kernel<<<dim3(SEQ / 16, nb), dim3(256), 0, stream>>>(Ebuf, rZ, wbuf);
    sumw_kernel<<<dim3(nb), dim3(256), 0, stream>>>(wbuf, sumw_all, b0);
    wxpart_kernel<<<dim3(DMODEL / 512, nb, KSPLIT), dim3(256), 0, stream>>>(
        x_bf, wbuf, wxp, b0);
  }
  final_kernel<<<dim3(DMODEL / 4, NBATCH), dim3(256), 0, stream>>>(
      wxp, sumw_all, Wv, bv, out);
}

// Round 9
// 380.607 us; speedup vs baseline: 1.3435x; 1.0272x over previous
//
#include <hip/hip_runtime.h>
#include <hip/hip_bf16.h>
#include <stdint.h>

#define NBATCH 16
#define SEQ    2048
#define DMODEL 1024
#define KSPLIT 8

typedef __attribute__((ext_vector_type(8))) short short8;   // 8 bf16 = 4 VGPRs
typedef __attribute__((ext_vector_type(4))) float f32x4;

struct __align__(8) bf4 { __hip_bfloat16 h[4]; };

__device__ __forceinline__ float bf2f(short s) {
  union { uint32_t u; float f; } c;
  c.u = ((uint32_t)(uint16_t)s) << 16;
  return c.f;
}

// async global -> LDS, 16B/lane. LDS dest = wave-uniform base + lane*16.
__device__ __forceinline__ void gload16(const void* g, void* l) {
  __builtin_amdgcn_global_load_lds(
      (const __attribute__((address_space(1))) void*)g,
      (__attribute__((address_space(3))) void*)l, 16, 0, 0);
}

#define BAR() __builtin_amdgcn_s_barrier()
#define WAIT_LGKM0()                                         \
  do {                                                       \
    asm volatile("s_waitcnt lgkmcnt(0)" ::: "memory");       \
    __builtin_amdgcn_sched_barrier(0);                       \
  } while (0)
#define WAIT_VM0()                                           \
  do {                                                       \
    asm volatile("s_waitcnt vmcnt(0)" ::: "memory");         \
  } while (0)

// ---------------------------------------------------------------------------
// 256x256-tile 8-wave GEMM, BK=64, dbuf 128KiB LDS, T2 swizzle, round-4
// schedule (stage next tile at ph1/ph2, vmcnt(0) at ph4). TP = output-tile
// pairing: one block processes TP consecutive at2 tiles sharing its B panel;
// the next tile's kt=0 stage is just another pipeline step (no cold prologue),
// epilogue runs inside the loop at i==15 after the VM0 drain.
// OUT-value = sum_e A[Arow][e]*B[Brow][e]  (A,B row-major, ld = DMODEL).
// MODE 0: OUT[Brow][Arow], Arow contiguous, j-packed 8B stores.
//         grid (ATILES/TP, BTILES).
// MODE 1: A=x (k rows), B=Y (q rows). E[k][q] = mask[k]?exp((s+v[k])/32):0
//         (scalar bf16 stores, 16-lane-contiguous in q); Zpart[cb][at2][q].
//         grid (16 = (bx&7)=qt, (bx>>3)*TP=at2base, nb).
template <int MODE, int TP>
__global__ __launch_bounds__(512, 2)
void gemmT_kernel(const __hip_bfloat16* __restrict__ Aall,
                  const __hip_bfloat16* __restrict__ Ball,
                  __hip_bfloat16* __restrict__ OUT, int ldo,
                  const int* __restrict__ mask,
                  const float* __restrict__ vball,
                  float* __restrict__ Zpart, int b0) {
  __shared__ __align__(16) char smem[131072 + 2048];  // tiles + red scratch
  const int t = threadIdx.x, lane = t & 63, wid = t >> 6;
  const int wm = wid >> 2, wn = wid & 3;
  const int g = lane >> 4, l15 = lane & 15, l7 = lane & 7;

  int at2base, bt2, cb = 0;
  const __hip_bfloat16* Bb;
  if constexpr (MODE == 0) {
    at2base = blockIdx.x * TP;
    bt2 = blockIdx.y;
    Bb = Ball + (size_t)bt2 * 256 * DMODEL;
  } else {
    cb = blockIdx.y;
    bt2 = blockIdx.x & 7;             // q-tile; bx%8 pins XCD to a Y panel
    at2base = (blockIdx.x >> 3) * TP; // first k-tile of this block's group
    Bb = Ball + ((size_t)(b0 + cb) * SEQ + bt2 * 256) * DMODEL;
  }
  const __hip_bfloat16* Abatch =
      (MODE == 0) ? Aall : Aall + (size_t)(b0 + cb) * SEQ * DMODEL;
  auto Aof = [&](int tp) {
    return Abatch + (size_t)(at2base + tp) * 256 * DMODEL;
  };

  const int srl = t >> 3;
  const int sc8 = (t & 7) ^ (srl & 7);          // pre-swizzled global col8
  const int pc8[2] = {g ^ l7, (4 + g) ^ l7};    // swizzled read col8

  auto stage_mat = [&](const __hip_bfloat16* gs, char* dst, int kt) {
#pragma unroll
    for (int h = 0; h < 2; ++h)
#pragma unroll
      for (int it = 0; it < 2; ++it)
        gload16(gs + (size_t)(h * 128 + it * 64 + srl) * DMODEL + kt * 64 + sc8 * 8,
                dst + h * 16384 + it * 8192 + wid * 1024);
  };

  f32x4 acc[8][4];
#pragma unroll
  for (int m = 0; m < 8; ++m)
#pragma unroll
    for (int n = 0; n < 4; ++n) acc[m][n] = (f32x4){0.f, 0.f, 0.f, 0.f};
  short8 afr[2][4], bfr[2][2][2];

#define LDA_Q(MH)                                                           \
  { _Pragma("unroll") for (int m = 0; m < 4; ++m) {                         \
      const int row = wm * 128 + ((MH) * 4 + m) * 16 + l15;                 \
      afr[0][m] = *(const short8*)(At + row * 128 + pc8[0] * 16);           \
      afr[1][m] = *(const short8*)(At + row * 128 + pc8[1] * 16);           \
    } }
#define LDB_Q(NH)                                                           \
  { _Pragma("unroll") for (int n = 0; n < 2; ++n) {                         \
      const int row = wn * 64 + ((NH) * 2 + n) * 16 + l15;                  \
      bfr[NH][0][n] = *(const short8*)(Bt + row * 128 + pc8[0] * 16);       \
      bfr[NH][1][n] = *(const short8*)(Bt + row * 128 + pc8[1] * 16);       \
    } }
#define MFMA_Q(MH, NH)                                                      \
  { __builtin_amdgcn_s_setprio(1);                                          \
    _Pragma("unroll") for (int kk = 0; kk < 2; ++kk)                        \
    _Pragma("unroll") for (int m = 0; m < 4; ++m)                           \
    _Pragma("unroll") for (int n = 0; n < 2; ++n)                           \
      acc[(MH)*4+m][(NH)*2+n] = __builtin_amdgcn_mfma_f32_16x16x32_bf16(    \
          afr[kk][m], bfr[NH][kk][n], acc[(MH)*4+m][(NH)*2+n], 0, 0, 0);    \
    __builtin_amdgcn_s_setprio(0); }

  // epilogue for one finished at2 tile; resets acc.
  auto EPI = [&](int at2) {
    if constexpr (MODE == 0) {
      const size_t orow0 = (size_t)bt2 * 256 + wn * 64 + l15;
      const int ocol0 = at2 * 256 + wm * 128 + g * 4;
#pragma unroll
      for (int mi = 0; mi < 8; ++mi)
#pragma unroll
        for (int ni = 0; ni < 4; ++ni) {
          bf4 pk;
#pragma unroll
          for (int j = 0; j < 4; ++j) pk.h[j] = __float2bfloat16(acc[mi][ni][j]);
          *(bf4*)(OUT + (orow0 + ni * 16) * ldo + ocol0 + mi * 16) = pk;
        }
    } else {
      const int b = b0 + cb;
      float zc[4] = {0.f, 0.f, 0.f, 0.f};
#pragma unroll
      for (int mi = 0; mi < 8; ++mi) {
        const int krow0 = at2 * 256 + wm * 128 + mi * 16 + g * 4;
        const int4 mk4 = *(const int4*)&mask[(size_t)b * SEQ + krow0];
        const float4 v4 = *(const float4*)&vball[(size_t)cb * SEQ + krow0 +
                                                 (size_t)0];
        const float4 vv = *(const float4*)&vball[(size_t)cb * SEQ + krow0];
        (void)v4;
#pragma unroll
        for (int j = 0; j < 4; ++j) {
          const int km = (j == 0) ? mk4.x : (j == 1) ? mk4.y : (j == 2) ? mk4.z : mk4.w;
          const float vj = (j == 0) ? vv.x : (j == 1) ? vv.y : (j == 2) ? vv.z : vv.w;
          __hip_bfloat16* Erow =
              OUT + ((size_t)cb * SEQ + krow0 + j) * (size_t)SEQ + bt2 * 256 + wn * 64;
#pragma unroll
          for (int ni = 0; ni < 4; ++ni) {
            const float e = km ? __expf((acc[mi][ni][j] + vj) * 0.03125f) : 0.f;
            zc[ni] += e;
            Erow[ni * 16 + l15] = __float2bfloat16(e);
          }
        }
      }
#pragma unroll
      for (int ni = 0; ni < 4; ++ni) {
        float v = zc[ni];
        v += __shfl_xor(v, 16);
        v += __shfl_xor(v, 32);
        zc[ni] = v;
      }
      float* red = (float*)(smem + 131072);  // dedicated scratch (bufs live)
      if (lane < 16) {
#pragma unroll
        for (int ni = 0; ni < 4; ++ni)
          red[wm * 256 + wn * 64 + ni * 16 + lane] = zc[ni];
      }
      __syncthreads();
      if (t < 256)
        Zpart[((size_t)cb * 8 + at2) * SEQ + bt2 * 256 + t] = red[t] + red[256 + t];
    }
#pragma unroll
    for (int m = 0; m < 8; ++m)
#pragma unroll
      for (int n = 0; n < 4; ++n) acc[m][n] = (f32x4){0.f, 0.f, 0.f, 0.f};
  };

  // prologue: first tile, kt 0 -> buf0
  stage_mat(Aof(0), smem, 0);
  stage_mat(Bb, smem + 32768, 0);
  WAIT_VM0();
  BAR();

  const int NI = 16 * TP;
#pragma unroll 1
  for (int ii = 0; ii < NI; ++ii) {
    const int p = ii & 1;
    const char* At = smem + (p << 16);
    const char* Bt = smem + 32768 + (p << 16);
    char* An = smem + ((p ^ 1) << 16);
    char* Bn = smem + 32768 + ((p ^ 1) << 16);
    const int kn = (ii + 1) & 15;
    // ph1
    LDA_Q(0) LDB_Q(0)
    if (ii + 1 < NI) stage_mat(Aof((ii + 1) >> 4), An, kn);
    BAR(); WAIT_LGKM0(); MFMA_Q(0, 0) BAR();
    // ph2
    LDB_Q(1)
    if (ii + 1 < NI) stage_mat(Bb, Bn, kn);
    BAR(); WAIT_LGKM0(); MFMA_Q(0, 1) BAR();
    // ph3
    LDA_Q(1)
    BAR(); WAIT_LGKM0(); MFMA_Q(1, 0) BAR();
    // ph4
    MFMA_Q(1, 1)
    WAIT_VM0();                       // next tile (or next tp's kt0) landed
    if ((ii & 15) == 15) EPI(at2base + (ii >> 4));  // epilogue; resets acc
    BAR();
  }
#undef LDA_Q
#undef LDB_Q
#undef MFMA_Q
}

// ---------------------------------------------------------------------------
// fp32 [DMODEL][DMODEL] -> bf16 transposed
__global__ void transpose_cvt_kernel(const float* __restrict__ in,
                                     __hip_bfloat16* __restrict__ outp) {
  __shared__ float tile[32][33];
  const int bx = blockIdx.x, by = blockIdx.y;
  const int tx = threadIdx.x & 31, ty = threadIdx.x >> 5;  // 32 x 8
#pragma unroll
  for (int r = 0; r < 32; r += 8)
    tile[ty + r][tx] = in[(size_t)(by * 32 + ty + r) * DMODEL + bx * 32 + tx];
  __syncthreads();
#pragma unroll
  for (int r = 0; r < 32; r += 8)
    outp[(size_t)(bx * 32 + ty + r) * DMODEL + by * 32 + tx] =
        __float2bfloat16(tile[tx][ty + r]);
}

// t2[d] = sum_e Wk[e][d]*bq[e]  (via WkT rows)
__global__ __launch_bounds__(256)
void prep_t2_kernel(const __hip_bfloat16* __restrict__ WkT,
                    const float* __restrict__ bq, float* __restrict__ t2) {
  const int wave = threadIdx.x >> 6, lane = threadIdx.x & 63;
  const int d = blockIdx.x * 4 + wave;
  const short8* kr = (const short8*)(WkT + (size_t)d * DMODEL);
  float a2 = 0.f;
#pragma unroll
  for (int h = 0; h < 2; ++h) {
    const short8 kv = kr[lane * 2 + h];
    const int e0 = lane * 16 + h * 8;
#pragma unroll
    for (int i = 0; i < 8; ++i) a2 += bf2f(kv[i]) * bq[e0 + i];
  }
  a2 += __shfl_down(a2, 32); a2 += __shfl_down(a2, 16); a2 += __shfl_down(a2, 8);
  a2 += __shfl_down(a2, 4);  a2 += __shfl_down(a2, 2);  a2 += __shfl_down(a2, 1);
  if (lane == 0) t2[d] = a2;
}

// fused: x fp32 -> x_bf (all batches) + vb[row] = x[row].t2
__global__ __launch_bounds__(256)
void cvtv_kernel(const float* __restrict__ x, const float* __restrict__ t2,
                 __hip_bfloat16* __restrict__ x_bf, float* __restrict__ vb) {
  const int wave = threadIdx.x >> 6, lane = threadIdx.x & 63;
  const size_t row = (size_t)blockIdx.x * 4 + wave;
  const float* xr = x + row * DMODEL;
  float a2 = 0.f;
#pragma unroll
  for (int p = 0; p < 4; ++p) {
    const int d = p * 256 + lane * 4;
    const float4 xv = *(const float4*)(xr + d);
    const float4 tv = *(const float4*)(t2 + d);
    a2 += xv.x * tv.x + xv.y * tv.y + xv.z * tv.z + xv.w * tv.w;
    bf4 pk;
    pk.h[0] = __float2bfloat16(xv.x); pk.h[1] = __float2bfloat16(xv.y);
    pk.h[2] = __float2bfloat16(xv.z); pk.h[3] = __float2bfloat16(xv.w);
    *(bf4*)(x_bf + row * DMODEL + d) = pk;
  }
  a2 += __shfl_down(a2, 32); a2 += __shfl_down(a2, 16); a2 += __shfl_down(a2, 8);
  a2 += __shfl_down(a2, 4);  a2 += __shfl_down(a2, 2);  a2 += __shfl_down(a2, 1);
  if (lane == 0) vb[row] = a2;
}

// rZ[cb][q] = 1 / sum_{at2<8} Zpart[cb][at2][q]  (0 if empty)
__global__ void zinv_kernel(const float* __restrict__ Zpart,
                            float* __restrict__ rZ, int n) {
  const int idx = blockIdx.x * 256 + threadIdx.x;
  if (idx >= n) return;
  const int cb = idx >> 11, q = idx & (SEQ - 1);
  float z = 0.f;
#pragma unroll
  for (int kt = 0; kt < 8; ++kt)
    z += Zpart[((size_t)cb * 8 + kt) * SEQ + q];
  rZ[(size_t)cb * SEQ + q] = (z > 0.f) ? (1.f / z) : 0.f;
}

// passB: w[k] = sum_q E[k][q] * rZ[q]  (rZ slice in regs, coalesced E rows)
__global__ __launch_bounds__(256)
void passB_kernel(const __hip_bfloat16* __restrict__ E,
                  const float* __restrict__ rZ,
                  float* __restrict__ wout) {
  const int t = threadIdx.x, lane = t & 63, wave = t >> 6;
  const int cb = blockIdx.y;
  float4 rzv[4][2];
#pragma unroll
  for (int it = 0; it < 4; ++it) {
    const float4* p = (const float4*)(rZ + (size_t)cb * SEQ + it * 512 + lane * 8);
    rzv[it][0] = p[0];
    rzv[it][1] = p[1];
  }
  const int kbase = blockIdx.x * 16 + wave * 4;
#pragma unroll
  for (int r = 0; r < 4; ++r) {
    const int k = kbase + r;
    const short8* Ep = (const short8*)(E + ((size_t)cb * SEQ + k) * SEQ);
    float s = 0.f;
#pragma unroll
    for (int it = 0; it < 4; ++it) {
      const short8 v = Ep[it * 64 + lane];
      const float* rz = (const float*)&rzv[it][0];
#pragma unroll
      for (int e = 0; e < 8; ++e) s += bf2f(v[e]) * rz[e];
    }
    s += __shfl_down(s, 32); s += __shfl_down(s, 16); s += __shfl_down(s, 8);
    s += __shfl_down(s, 4);  s += __shfl_down(s, 2);  s += __shfl_down(s, 1);
    if (lane == 0) wout[(size_t)cb * SEQ + k] = s;
  }
}

// sumw_all[b] = sum_k w[k]
__global__ void sumw_kernel(const float* __restrict__ w,
                            float* __restrict__ sumw_all, int b0) {
  __shared__ float sred[4];
  const int t = threadIdx.x, lane = t & 63, wave = t >> 6;
  const int cb = blockIdx.x;
  float v = 0.f;
  for (int k = t; k < SEQ; k += 256) v += w[(size_t)cb * SEQ + k];
  v += __shfl_down(v, 32); v += __shfl_down(v, 16); v += __shfl_down(v, 8);
  v += __shfl_down(v, 4);  v += __shfl_down(v, 2);  v += __shfl_down(v, 1);
  if (lane == 0) sred[wave] = v;
  __syncthreads();
  if (t == 0) sumw_all[b0 + cb] = sred[0] + sred[1] + sred[2] + sred[3];
}

// wxp[kq][b][d] = sum_{k in chunk kq} w[k] * x_bf[b][k][d]
__global__ void wxpart_kernel(const __hip_bfloat16* __restrict__ x_bf,
                              const float* __restrict__ w,
                              float* __restrict__ wxp, int b0) {
  const int dt = blockIdx.x, cb = blockIdx.y, kq = blockIdx.z;
  const int b = b0 + cb;
  const int dp = dt * 256 + threadIdx.x;
  const __hip_bfloat16* xb =
      x_bf + ((size_t)b * SEQ + (size_t)kq * (SEQ / KSPLIT)) * DMODEL;
  const float* wb = w + (size_t)cb * SEQ + (size_t)kq * (SEQ / KSPLIT);
  float a0 = 0.f, a1 = 0.f;
#pragma unroll 4
  for (int k = 0; k < SEQ / KSPLIT; ++k) {
    const float wk = wb[k];
    const uint32_t pv = *(const uint32_t*)(xb + (size_t)k * DMODEL + dp * 2);
    a0 += wk * bf2f((short)(pv & 0xffff));
    a1 += wk * bf2f((short)(pv >> 16));
  }
  float2* o = (float2*)&wxp[((size_t)kq * NBATCH + b) * DMODEL + dp * 2];
  *o = make_float2(a0, a1);
}

// out[b][e] = ( sum_d (sum_kq wxp[kq][b][d]) * Wv[e][d] + sumw[b]*bv[e] ) / SEQ
__global__ void final_kernel(const float* __restrict__ wxp,
                             const float* __restrict__ sumw_all,
                             const float* __restrict__ Wv,
                             const float* __restrict__ bv,
                             float* __restrict__ out) {
  const int b = blockIdx.y, eg = blockIdx.x;
  const int wave = threadIdx.x >> 6, lane = threadIdx.x & 63;
  const int e = eg * 4 + wave;
  float acc = 0.f;
  for (int d = lane; d < DMODEL; d += 64) {
    float wx = 0.f;
#pragma unroll
    for (int kq = 0; kq < KSPLIT; ++kq)
      wx += wxp[((size_t)kq * NBATCH + b) * DMODEL + d];
    acc += wx * Wv[(size_t)e * DMODEL + d];
  }
  acc += __shfl_down(acc, 32); acc += __shfl_down(acc, 16);
  acc += __shfl_down(acc, 8);  acc += __shfl_down(acc, 4);
  acc += __shfl_down(acc, 2);  acc += __shfl_down(acc, 1);
  if (lane == 0)
    out[(size_t)b * DMODEL + e] =
        (acc + sumw_all[b] * bv[e]) * (1.f / (float)SEQ);
}

// ---------------------------------------------------------------------------
extern "C" void kernel_launch(void* const* d_in, const int* in_sizes, int n_in,
                              void* d_out, int out_size, void* d_ws, size_t ws_size,
                              hipStream_t stream) {
  const float* x  = (const float*)d_in[0];
  const int* mask = (const int*)d_in[1];
  const float* Wq = (const float*)d_in[2];
  const float* bq = (const float*)d_in[3];
  const float* Wk = (const float*)d_in[4];
  const float* bk = (const float*)d_in[5];
  const float* Wv = (const float*)d_in[6];
  const float* bv = (const float*)d_in[7];
  float* out = (float*)d_out;
  (void)bk;

  char* ws = (char*)d_ws;
  size_t off = 0;
  auto alloc = [&](size_t bytes) -> void* {
    void* p = ws + off;
    off += (bytes + 255) & ~(size_t)255;
    return p;
  };
  // ---- persistent ----
  __hip_bfloat16* Mt_bf  = (__hip_bfloat16*)alloc((size_t)DMODEL * DMODEL * 2);
  __hip_bfloat16* WqT_bf = (__hip_bfloat16*)alloc((size_t)DMODEL * DMODEL * 2);
  __hip_bfloat16* WkT_bf = (__hip_bfloat16*)alloc((size_t)DMODEL * DMODEL * 2);
  float* wxp      = (float*)alloc((size_t)KSPLIT * NBATCH * DMODEL * 4);
  float* sumw_all = (float*)alloc((size_t)NBATCH * 4);
  float* t2       = (float*)alloc((size_t)DMODEL * 4);
  __hip_bfloat16* x_bf = (__hip_bfloat16*)alloc((size_t)NBATCH * SEQ * DMODEL * 2);
  __hip_bfloat16* Yb   = (__hip_bfloat16*)alloc((size_t)NBATCH * SEQ * DMODEL * 2);
  float* vb = (float*)alloc((size_t)NBATCH * SEQ * 4);
  const size_t fixed = off;

  // ---- per-chunk (E + small per-batch) ----
  const size_t per_batch = (size_t)SEQ * SEQ * 2       // E
                         + (size_t)8 * SEQ * 4         // Zpart
                         + (size_t)2 * SEQ * 4 + 8 * 256;
  long avail = (long)ws_size - (long)fixed;
  int NB = (int)(avail / (long)per_batch);
  if (NB < 1) NB = 1;
  if (NB > NBATCH) NB = NBATCH;
  while (NBATCH % NB) --NB;   // NB in {1,2,4,8,16}
  __hip_bfloat16* Ebuf = (__hip_bfloat16*)alloc((size_t)NB * SEQ * SEQ * 2);
  float* Zpart = (float*)alloc((size_t)NB * 8 * SEQ * 4);
  float* rZ    = (float*)alloc((size_t)NB * SEQ * 4);
  float* wbuf  = (float*)alloc((size_t)NB * SEQ * 4);

  // ---- prep ----
  transpose_cvt_kernel<<<dim3(32, 32), dim3(256), 0, stream>>>(Wq, WqT_bf);
  transpose_cvt_kernel<<<dim3(32, 32), dim3(256), 0, stream>>>(Wk, WkT_bf);
  // Mt[d'][d] = sum_e WkT[d'][e]*WqT[d][e]   (TP=1: max parallelism)
  gemmT_kernel<0, 1><<<dim3(4, 4), dim3(512), 0, stream>>>(
      WqT_bf, WkT_bf, Mt_bf, DMODEL, nullptr, nullptr, nullptr, 0);
  prep_t2_kernel<<<dim3(256), dim3(256), 0, stream>>>(WkT_bf, bq, t2);
  cvtv_kernel<<<dim3(NBATCH * SEQ / 4), dim3(256), 0, stream>>>(x, t2, x_bf, vb);
  // Y[q][d'] = sum_d x[q][d]*Mt[d'][d]   (TP=2: 256 blocks, 1 round)
  gemmT_kernel<0, 2><<<dim3(2, NBATCH * 8), dim3(512), 0, stream>>>(
      Mt_bf, x_bf, Yb, DMODEL, nullptr, nullptr, nullptr, 0);

  for (int b0 = 0; b0 < NBATCH; b0 += NB) {
    const int nb = NB;
    // E[k][q] + Zpart  (TP=4: 16*nb blocks of 4 k-tiles, 1 round at nb=16)
    gemmT_kernel<1, 4><<<dim3(16, nb), dim3(512), 0, stream>>>(
        x_bf, Yb, Ebuf, SEQ, mask, vb, Zpart, b0);
    zinv_kernel<<<dim3((nb * SEQ + 255) / 256), dim3(256), 0, stream>>>(
        Zpart, rZ, nb * SEQ);
    passB_kernel<<<dim3(SEQ / 16, nb), dim3(256), 0, stream>>>(Ebuf, rZ, wbuf);
    sumw_kernel<<<dim3(nb), dim3(256), 0, stream>>>(wbuf, sumw_all, b0);
    wxpart_kernel<<<dim3(DMODEL / 512, nb, KSPLIT), dim3(256), 0, stream>>>(
        x_bf, wbuf, wxp, b0);
  }
  final_kernel<<<dim3(DMODEL / 4, NBATCH), dim3(256), 0, stream>>>(
      wxp, sumw_all, Wv, bv, out);
}

// Round 10
// 355.541 us; speedup vs baseline: 1.4383x; 1.0705x over previous
//
#include <hip/hip_runtime.h>
#include <hip/hip_bf16.h>
#include <stdint.h>

#define NBATCH 16
#define SEQ    2048
#define DMODEL 1024
#define KSPLIT 8

// exp((s+v)/32) * 2^-4  ==  exp( s*CS + (v*CS - 4*ln2) )
#define CS      0.03125f
#define NEG4LN2 2.772588722f

typedef __attribute__((ext_vector_type(8))) short short8;   // 8 bf16 = 4 VGPRs
typedef __attribute__((ext_vector_type(4))) float f32x4;

struct __align__(8) bf4 { __hip_bfloat16 h[4]; };

__device__ __forceinline__ float bf2f(short s) {
  union { uint32_t u; float f; } c;
  c.u = ((uint32_t)(uint16_t)s) << 16;
  return c.f;
}

// async global -> LDS, 16B/lane. LDS dest = wave-uniform base + lane*16.
__device__ __forceinline__ void gload16(const void* g, void* l) {
  __builtin_amdgcn_global_load_lds(
      (const __attribute__((address_space(1))) void*)g,
      (__attribute__((address_space(3))) void*)l, 16, 0, 0);
}

#define BAR() __builtin_amdgcn_s_barrier()
#define WAIT_LGKM0()                                         \
  do {                                                       \
    asm volatile("s_waitcnt lgkmcnt(0)" ::: "memory");       \
    __builtin_amdgcn_sched_barrier(0);                       \
  } while (0)
#define WAIT_VM0()                                           \
  do {                                                       \
    asm volatile("s_waitcnt vmcnt(0)" ::: "memory");         \
  } while (0)

// ---------------------------------------------------------------------------
// 256x256-tile 8-wave GEMM, BK=64, dbuf 128KiB LDS, T2 swizzle, round-4
// schedule with TP output-tile pairing (round 9).
// OUT-value = sum_e A[Arow][e]*B[Brow][e]  (A,B row-major, ld = DMODEL).
// MODE 0: bf16 OUT[Brow][Arow], Arow contiguous, j-packed 8B stores.
// MODE 1: A=x (k rows), B=Y (q rows). E8[k][q] = fp8_e4m3( exp(s*CS + vb'[k]) )
//         (vb' carries the k-mask as -1e30 and the 2^-4 scale);
//         Zpart[cb][at2][q] from the same scaled values (scale cancels in w).
template <int MODE, int TP>
__global__ __launch_bounds__(512, 2)
void gemmT_kernel(const __hip_bfloat16* __restrict__ Aall,
                  const __hip_bfloat16* __restrict__ Ball,
                  __hip_bfloat16* __restrict__ OUT, int ldo,
                  const float* __restrict__ vball,
                  float* __restrict__ Zpart, int b0) {
  __shared__ __align__(16) char smem[131072 + 2048];  // tiles + red scratch
  const int t = threadIdx.x, lane = t & 63, wid = t >> 6;
  const int wm = wid >> 2, wn = wid & 3;
  const int g = lane >> 4, l15 = lane & 15, l7 = lane & 7;

  int at2base, bt2, cb = 0;
  const __hip_bfloat16* Bb;
  if constexpr (MODE == 0) {
    at2base = blockIdx.x * TP;
    bt2 = blockIdx.y;
    Bb = Ball + (size_t)bt2 * 256 * DMODEL;
  } else {
    cb = blockIdx.y;
    bt2 = blockIdx.x & 7;             // q-tile; bx%8 pins XCD to a Y panel
    at2base = (blockIdx.x >> 3) * TP; // first k-tile of this block's group
    Bb = Ball + ((size_t)(b0 + cb) * SEQ + bt2 * 256) * DMODEL;
  }
  const __hip_bfloat16* Abatch =
      (MODE == 0) ? Aall : Aall + (size_t)(b0 + cb) * SEQ * DMODEL;
  auto Aof = [&](int tp) {
    return Abatch + (size_t)(at2base + tp) * 256 * DMODEL;
  };

  const int srl = t >> 3;
  const int sc8 = (t & 7) ^ (srl & 7);          // pre-swizzled global col8
  const int pc8[2] = {g ^ l7, (4 + g) ^ l7};    // swizzled read col8

  auto stage_mat = [&](const __hip_bfloat16* gs, char* dst, int kt) {
#pragma unroll
    for (int h = 0; h < 2; ++h)
#pragma unroll
      for (int it = 0; it < 2; ++it)
        gload16(gs + (size_t)(h * 128 + it * 64 + srl) * DMODEL + kt * 64 + sc8 * 8,
                dst + h * 16384 + it * 8192 + wid * 1024);
  };

  f32x4 acc[8][4];
#pragma unroll
  for (int m = 0; m < 8; ++m)
#pragma unroll
    for (int n = 0; n < 4; ++n) acc[m][n] = (f32x4){0.f, 0.f, 0.f, 0.f};
  short8 afr[2][4], bfr[2][2][2];

#define LDA_Q(MH)                                                           \
  { _Pragma("unroll") for (int m = 0; m < 4; ++m) {                         \
      const int row = wm * 128 + ((MH) * 4 + m) * 16 + l15;                 \
      afr[0][m] = *(const short8*)(At + row * 128 + pc8[0] * 16);           \
      afr[1][m] = *(const short8*)(At + row * 128 + pc8[1] * 16);           \
    } }
#define LDB_Q(NH)                                                           \
  { _Pragma("unroll") for (int n = 0; n < 2; ++n) {                         \
      const int row = wn * 64 + ((NH) * 2 + n) * 16 + l15;                  \
      bfr[NH][0][n] = *(const short8*)(Bt + row * 128 + pc8[0] * 16);       \
      bfr[NH][1][n] = *(const short8*)(Bt + row * 128 + pc8[1] * 16);       \
    } }
#define MFMA_Q(MH, NH)                                                      \
  { __builtin_amdgcn_s_setprio(1);                                          \
    _Pragma("unroll") for (int kk = 0; kk < 2; ++kk)                        \
    _Pragma("unroll") for (int m = 0; m < 4; ++m)                           \
    _Pragma("unroll") for (int n = 0; n < 2; ++n)                           \
      acc[(MH)*4+m][(NH)*2+n] = __builtin_amdgcn_mfma_f32_16x16x32_bf16(    \
          afr[kk][m], bfr[NH][kk][n], acc[(MH)*4+m][(NH)*2+n], 0, 0, 0);    \
    __builtin_amdgcn_s_setprio(0); }

  // epilogue for one finished at2 tile; resets acc.
  auto EPI = [&](int at2) {
    if constexpr (MODE == 0) {
      const size_t orow0 = (size_t)bt2 * 256 + wn * 64 + l15;
      const int ocol0 = at2 * 256 + wm * 128 + g * 4;
#pragma unroll
      for (int mi = 0; mi < 8; ++mi)
#pragma unroll
        for (int ni = 0; ni < 4; ++ni) {
          bf4 pk;
#pragma unroll
          for (int j = 0; j < 4; ++j) pk.h[j] = __float2bfloat16(acc[mi][ni][j]);
          *(bf4*)(OUT + (orow0 + ni * 16) * ldo + ocol0 + mi * 16) = pk;
        }
    } else {
      uint8_t* E8 = (uint8_t*)OUT;
      float zc[4] = {0.f, 0.f, 0.f, 0.f};
#pragma unroll
      for (int mi = 0; mi < 8; ++mi) {
        const int krow0 = at2 * 256 + wm * 128 + mi * 16 + g * 4;
        const float4 vv = *(const float4*)&vball[(size_t)cb * SEQ + krow0];
#pragma unroll
        for (int j = 0; j < 4; ++j) {
          const float vj = (j == 0) ? vv.x : (j == 1) ? vv.y : (j == 2) ? vv.z : vv.w;
          uint8_t* Erow = E8 + ((size_t)cb * SEQ + krow0 + j) * (size_t)SEQ +
                          bt2 * 256 + wn * 64 + l15;
          float ev[4];
#pragma unroll
          for (int ni = 0; ni < 4; ++ni) {
            ev[ni] = __expf(fmaf(acc[mi][ni][j], CS, vj));
            zc[ni] += ev[ni];
          }
          const unsigned p01 =
              __builtin_amdgcn_cvt_pk_fp8_f32(ev[0], ev[1], 0, false);
          const unsigned p23 =
              __builtin_amdgcn_cvt_pk_fp8_f32(ev[2], ev[3], 0, false);
          Erow[0]  = (uint8_t)p01;
          Erow[16] = (uint8_t)(p01 >> 8);
          Erow[32] = (uint8_t)p23;
          Erow[48] = (uint8_t)(p23 >> 8);
        }
      }
#pragma unroll
      for (int ni = 0; ni < 4; ++ni) {
        float v = zc[ni];
        v += __shfl_xor(v, 16);
        v += __shfl_xor(v, 32);
        zc[ni] = v;
      }
      float* red = (float*)(smem + 131072);  // dedicated scratch (bufs live)
      if (lane < 16) {
#pragma unroll
        for (int ni = 0; ni < 4; ++ni)
          red[wm * 256 + wn * 64 + ni * 16 + lane] = zc[ni];
      }
      __syncthreads();
      if (t < 256)
        Zpart[((size_t)cb * 8 + at2) * SEQ + bt2 * 256 + t] = red[t] + red[256 + t];
    }
#pragma unroll
    for (int m = 0; m < 8; ++m)
#pragma unroll
      for (int n = 0; n < 4; ++n) acc[m][n] = (f32x4){0.f, 0.f, 0.f, 0.f};
  };

  // prologue: first tile, kt 0 -> buf0
  stage_mat(Aof(0), smem, 0);
  stage_mat(Bb, smem + 32768, 0);
  WAIT_VM0();
  BAR();

  const int NI = 16 * TP;
#pragma unroll 1
  for (int ii = 0; ii < NI; ++ii) {
    const int p = ii & 1;
    const char* At = smem + (p << 16);
    const char* Bt = smem + 32768 + (p << 16);
    char* An = smem + ((p ^ 1) << 16);
    char* Bn = smem + 32768 + ((p ^ 1) << 16);
    const int kn = (ii + 1) & 15;
    // ph1
    LDA_Q(0) LDB_Q(0)
    if (ii + 1 < NI) stage_mat(Aof((ii + 1) >> 4), An, kn);
    BAR(); WAIT_LGKM0(); MFMA_Q(0, 0) BAR();
    // ph2
    LDB_Q(1)
    if (ii + 1 < NI) stage_mat(Bb, Bn, kn);
    BAR(); WAIT_LGKM0(); MFMA_Q(0, 1) BAR();
    // ph3
    LDA_Q(1)
    BAR(); WAIT_LGKM0(); MFMA_Q(1, 0) BAR();
    // ph4
    MFMA_Q(1, 1)
    WAIT_VM0();                       // next tile (or next tp's kt0) landed
    if ((ii & 15) == 15) EPI(at2base + (ii >> 4));  // epilogue; resets acc
    BAR();
  }
#undef LDA_Q
#undef LDB_Q
#undef MFMA_Q
}

// ---------------------------------------------------------------------------
// fp32 [DMODEL][DMODEL] -> bf16 transposed
__global__ void transpose_cvt_kernel(const float* __restrict__ in,
                                     __hip_bfloat16* __restrict__ outp) {
  __shared__ float tile[32][33];
  const int bx = blockIdx.x, by = blockIdx.y;
  const int tx = threadIdx.x & 31, ty = threadIdx.x >> 5;  // 32 x 8
#pragma unroll
  for (int r = 0; r < 32; r += 8)
    tile[ty + r][tx] = in[(size_t)(by * 32 + ty + r) * DMODEL + bx * 32 + tx];
  __syncthreads();
#pragma unroll
  for (int r = 0; r < 32; r += 8)
    outp[(size_t)(bx * 32 + ty + r) * DMODEL + by * 32 + tx] =
        __float2bfloat16(tile[tx][ty + r]);
}

// t2[d] = sum_e Wk[e][d]*bq[e]  (via WkT rows)
__global__ __launch_bounds__(256)
void prep_t2_kernel(const __hip_bfloat16* __restrict__ WkT,
                    const float* __restrict__ bq, float* __restrict__ t2) {
  const int wave = threadIdx.x >> 6, lane = threadIdx.x & 63;
  const int d = blockIdx.x * 4 + wave;
  const short8* kr = (const short8*)(WkT + (size_t)d * DMODEL);
  float a2 = 0.f;
#pragma unroll
  for (int h = 0; h < 2; ++h) {
    const short8 kv = kr[lane * 2 + h];
    const int e0 = lane * 16 + h * 8;
#pragma unroll
    for (int i = 0; i < 8; ++i) a2 += bf2f(kv[i]) * bq[e0 + i];
  }
  a2 += __shfl_down(a2, 32); a2 += __shfl_down(a2, 16); a2 += __shfl_down(a2, 8);
  a2 += __shfl_down(a2, 4);  a2 += __shfl_down(a2, 2);  a2 += __shfl_down(a2, 1);
  if (lane == 0) t2[d] = a2;
}

// fused: x fp32 -> x_bf (all batches) + vb'[row] = mask ? x.t2*CS - 4ln2 : -1e30
__global__ __launch_bounds__(256)
void cvtv_kernel(const float* __restrict__ x, const float* __restrict__ t2,
                 const int* __restrict__ mask,
                 __hip_bfloat16* __restrict__ x_bf, float* __restrict__ vb) {
  const int wave = threadIdx.x >> 6, lane = threadIdx.x & 63;
  const size_t row = (size_t)blockIdx.x * 4 + wave;
  const float* xr = x + row * DMODEL;
  float a2 = 0.f;
#pragma unroll
  for (int p = 0; p < 4; ++p) {
    const int d = p * 256 + lane * 4;
    const float4 xv = *(const float4*)(xr + d);
    const float4 tv = *(const float4*)(t2 + d);
    a2 += xv.x * tv.x + xv.y * tv.y + xv.z * tv.z + xv.w * tv.w;
    bf4 pk;
    pk.h[0] = __float2bfloat16(xv.x); pk.h[1] = __float2bfloat16(xv.y);
    pk.h[2] = __float2bfloat16(xv.z); pk.h[3] = __float2bfloat16(xv.w);
    *(bf4*)(x_bf + row * DMODEL + d) = pk;
  }
  a2 += __shfl_down(a2, 32); a2 += __shfl_down(a2, 16); a2 += __shfl_down(a2, 8);
  a2 += __shfl_down(a2, 4);  a2 += __shfl_down(a2, 2);  a2 += __shfl_down(a2, 1);
  if (lane == 0)
    vb[row] = mask[row] ? fmaf(a2, CS, -NEG4LN2) : -1e30f;
}

// rZ[cb][q] = 1 / sum_{at2<8} Zpart[cb][at2][q]  (0 if empty)
__global__ void zinv_kernel(const float* __restrict__ Zpart,
                            float* __restrict__ rZ, int n) {
  const int idx = blockIdx.x * 256 + threadIdx.x;
  if (idx >= n) return;
  const int cb = idx >> 11, q = idx & (SEQ - 1);
  float z = 0.f;
#pragma unroll
  for (int kt = 0; kt < 8; ++kt)
    z += Zpart[((size_t)cb * 8 + kt) * SEQ + q];
  rZ[(size_t)cb * SEQ + q] = (z > 0.f) ? (1.f / z) : 0.f;
}

// passB: w[k] = sum_q E8[k][q] * rZ[q]  (fp8 E; scale cancels vs scaled Z)
__global__ __launch_bounds__(256)
void passB_kernel(const uint8_t* __restrict__ E8,
                  const float* __restrict__ rZ,
                  float* __restrict__ wout) {
  const int t = threadIdx.x, lane = t & 63, wave = t >> 6;
  const int cb = blockIdx.y;
  float4 rzv[4][2];
#pragma unroll
  for (int it = 0; it < 4; ++it) {
    const float4* p = (const float4*)(rZ + (size_t)cb * SEQ + it * 512 + lane * 8);
    rzv[it][0] = p[0];
    rzv[it][1] = p[1];
  }
  const int kbase = blockIdx.x * 16 + wave * 4;
#pragma unroll
  for (int r = 0; r < 4; ++r) {
    const int k = kbase + r;
    const uint2* Ep = (const uint2*)(E8 + ((size_t)cb * SEQ + k) * SEQ);
    float s = 0.f;
#pragma unroll
    for (int it = 0; it < 4; ++it) {
      const uint2 v = Ep[it * 64 + lane];
      const float* rz = (const float*)&rzv[it][0];
      s += __builtin_amdgcn_cvt_f32_fp8(v.x, 0) * rz[0];
      s += __builtin_amdgcn_cvt_f32_fp8(v.x, 1) * rz[1];
      s += __builtin_amdgcn_cvt_f32_fp8(v.x, 2) * rz[2];
      s += __builtin_amdgcn_cvt_f32_fp8(v.x, 3) * rz[3];
      s += __builtin_amdgcn_cvt_f32_fp8(v.y, 0) * rz[4];
      s += __builtin_amdgcn_cvt_f32_fp8(v.y, 1) * rz[5];
      s += __builtin_amdgcn_cvt_f32_fp8(v.y, 2) * rz[6];
      s += __builtin_amdgcn_cvt_f32_fp8(v.y, 3) * rz[7];
    }
    s += __shfl_down(s, 32); s += __shfl_down(s, 16); s += __shfl_down(s, 8);
    s += __shfl_down(s, 4);  s += __shfl_down(s, 2);  s += __shfl_down(s, 1);
    if (lane == 0) wout[(size_t)cb * SEQ + k] = s;
  }
}

// sumw_all[b] = sum_k w[k]
__global__ void sumw_kernel(const float* __restrict__ w,
                            float* __restrict__ sumw_all, int b0) {
  __shared__ float sred[4];
  const int t = threadIdx.x, lane = t & 63, wave = t >> 6;
  const int cb = blockIdx.x;
  float v = 0.f;
  for (int k = t; k < SEQ; k += 256) v += w[(size_t)cb * SEQ + k];
  v += __shfl_down(v, 32); v += __shfl_down(v, 16); v += __shfl_down(v, 8);
  v += __shfl_down(v, 4);  v += __shfl_down(v, 2);  v += __shfl_down(v, 1);
  if (lane == 0) sred[wave] = v;
  __syncthreads();
  if (t == 0) sumw_all[b0 + cb] = sred[0] + sred[1] + sred[2] + sred[3];
}

// wxp[kq][b][d] = sum_{k in chunk kq} w[k] * x_bf[b][k][d]
__global__ void wxpart_kernel(const __hip_bfloat16* __restrict__ x_bf,
                              const float* __restrict__ w,
                              float* __restrict__ wxp, int b0) {
  const int dt = blockIdx.x, cb = blockIdx.y, kq = blockIdx.z;
  const int b = b0 + cb;
  const int dp = dt * 256 + threadIdx.x;
  const __hip_bfloat16* xb =
      x_bf + ((size_t)b * SEQ + (size_t)kq * (SEQ / KSPLIT)) * DMODEL;
  const float* wb = w + (size_t)cb * SEQ + (size_t)kq * (SEQ / KSPLIT);
  float a0 = 0.f, a1 = 0.f;
#pragma unroll 4
  for (int k = 0; k < SEQ / KSPLIT; ++k) {
    const float wk = wb[k];
    const uint32_t pv = *(const uint32_t*)(xb + (size_t)k * DMODEL + dp * 2);
    a0 += wk * bf2f((short)(pv & 0xffff));
    a1 += wk * bf2f((short)(pv >> 16));
  }
  float2* o = (float2*)&wxp[((size_t)kq * NBATCH + b) * DMODEL + dp * 2];
  *o = make_float2(a0, a1);
}

// out[b][e] = ( sum_d (sum_kq wxp[kq][b][d]) * Wv[e][d] + sumw[b]*bv[e] ) / SEQ
__global__ void final_kernel(const float* __restrict__ wxp,
                             const float* __restrict__ sumw_all,
                             const float* __restrict__ Wv,
                             const float* __restrict__ bv,
                             float* __restrict__ out) {
  const int b = blockIdx.y, eg = blockIdx.x;
  const int wave = threadIdx.x >> 6, lane = threadIdx.x & 63;
  const int e = eg * 4 + wave;
  float acc = 0.f;
  for (int d = lane; d < DMODEL; d += 64) {
    float wx = 0.f;
#pragma unroll
    for (int kq = 0; kq < KSPLIT; ++kq)
      wx += wxp[((size_t)kq * NBATCH + b) * DMODEL + d];
    acc += wx * Wv[(size_t)e * DMODEL + d];
  }
  acc += __shfl_down(acc, 32); acc += __shfl_down(acc, 16);
  acc += __shfl_down(acc, 8);  acc += __shfl_down(acc, 4);
  acc += __shfl_down(acc, 2);  acc += __shfl_down(acc, 1);
  if (lane == 0)
    out[(size_t)b * DMODEL + e] =
        (acc + sumw_all[b] * bv[e]) * (1.f / (float)SEQ);
}

// ---------------------------------------------------------------------------
extern "C" void kernel_launch(void* const* d_in, const int* in_sizes, int n_in,
                              void* d_out, int out_size, void* d_ws, size_t ws_size,
                              hipStream_t stream) {
  const float* x  = (const float*)d_in[0];
  const int* mask = (const int*)d_in[1];
  const float* Wq = (const float*)d_in[2];
  const float* bq = (const float*)d_in[3];
  const float* Wk = (const float*)d_in[4];
  const float* bk = (const float*)d_in[5];
  const float* Wv = (const float*)d_in[6];
  const float* bv = (const float*)d_in[7];
  float* out = (float*)d_out;
  (void)bk;

  char* ws = (char*)d_ws;
  size_t off = 0;
  auto alloc = [&](size_t bytes) -> void* {
    void* p = ws + off;
    off += (bytes + 255) & ~(size_t)255;
    return p;
  };
  // ---- persistent ----
  __hip_bfloat16* Mt_bf  = (__hip_bfloat16*)alloc((size_t)DMODEL * DMODEL * 2);
  __hip_bfloat16* WqT_bf = (__hip_bfloat16*)alloc((size_t)DMODEL * DMODEL * 2);
  __hip_bfloat16* WkT_bf = (__hip_bfloat16*)alloc((size_t)DMODEL * DMODEL * 2);
  float* wxp      = (float*)alloc((size_t)KSPLIT * NBATCH * DMODEL * 4);
  float* sumw_all = (float*)alloc((size_t)NBATCH * 4);
  float* t2       = (float*)alloc((size_t)DMODEL * 4);
  __hip_bfloat16* x_bf = (__hip_bfloat16*)alloc((size_t)NBATCH * SEQ * DMODEL * 2);
  __hip_bfloat16* Yb   = (__hip_bfloat16*)alloc((size_t)NBATCH * SEQ * DMODEL * 2);
  float* vb = (float*)alloc((size_t)NBATCH * SEQ * 4);
  const size_t fixed = off;

  // ---- per-chunk (E fp8 + small per-batch) ----
  const size_t per_batch = (size_t)SEQ * SEQ * 1       // E (fp8)
                         + (size_t)8 * SEQ * 4         // Zpart
                         + (size_t)2 * SEQ * 4 + 8 * 256;
  long avail = (long)ws_size - (long)fixed;
  int NB = (int)(avail / (long)per_batch);
  if (NB < 1) NB = 1;
  if (NB > NBATCH) NB = NBATCH;
  while (NBATCH % NB) --NB;   // NB in {1,2,4,8,16}
  uint8_t* Ebuf = (uint8_t*)alloc((size_t)NB * SEQ * SEQ * 1);
  float* Zpart = (float*)alloc((size_t)NB * 8 * SEQ * 4);
  float* rZ    = (float*)alloc((size_t)NB * SEQ * 4);
  float* wbuf  = (float*)alloc((size_t)NB * SEQ * 4);

  // ---- prep ----
  transpose_cvt_kernel<<<dim3(32, 32), dim3(256), 0, stream>>>(Wq, WqT_bf);
  transpose_cvt_kernel<<<dim3(32, 32), dim3(256), 0, stream>>>(Wk, WkT_bf);
  // Mt[d'][d] = sum_e WkT[d'][e]*WqT[d][e]
  gemmT_kernel<0, 1><<<dim3(4, 4), dim3(512), 0, stream>>>(
      WqT_bf, WkT_bf, Mt_bf, DMODEL, nullptr, nullptr, 0);
  prep_t2_kernel<<<dim3(256), dim3(256), 0, stream>>>(WkT_bf, bq, t2);
  cvtv_kernel<<<dim3(NBATCH * SEQ / 4), dim3(256), 0, stream>>>(
      x, t2, mask, x_bf, vb);
  // Y[q][d'] = sum_d x[q][d]*Mt[d'][d]
  gemmT_kernel<0, 2><<<dim3(2, NBATCH * 8), dim3(512), 0, stream>>>(
      Mt_bf, x_bf, Yb, DMODEL, nullptr, nullptr, 0);

  for (int b0 = 0; b0 < NBATCH; b0 += NB) {
    const int nb = NB;
    // E8[k][q] + Zpart
    gemmT_kernel<1, 4><<<dim3(16, nb), dim3(512), 0, stream>>>(
        x_bf, Yb, (__hip_bfloat16*)Ebuf, SEQ, vb, Zpart, b0);
    zinv_kernel<<<dim3((nb * SEQ + 255) / 256), dim3(256), 0, stream>>>(
        Zpart, rZ, nb * SEQ);
    passB_kernel<<<dim3(SEQ / 16, nb), dim3(256), 0, stream>>>(Ebuf, rZ, wbuf);
    sumw_kernel<<<dim3(nb), dim3(256), 0, stream>>>(wbuf, sumw_all, b0);
    wxpart_kernel<<<dim3(DMODEL / 512, nb, KSPLIT), dim3(256), 0, stream>>>(
        x_bf, wbuf, wxp, b0);
  }
  final_kernel<<<dim3(DMODEL / 4, NBATCH), dim3(256), 0, stream>>>(
      wxp, sumw_all, Wv, bv, out);
}

// Round 11
// 321.395 us; speedup vs baseline: 1.5911x; 1.1062x over previous
//
#include <hip/hip_runtime.h>
#include <hip/hip_bf16.h>
#include <stdint.h>

#define NBATCH 16
#define SEQ    2048
#define DMODEL 1024
#define KSPLIT 8

// exp((s+v)/32) * 2^-4 ; s comes from int8 GEMM as s_int = 1024*s_raw
#define CS      0.03125f
#define KSC     3.0517578125e-5f   // CS/1024
#define NEG4LN2 2.772588722f

typedef __attribute__((ext_vector_type(8))) short short8;
typedef __attribute__((ext_vector_type(4))) float f32x4;
typedef __attribute__((ext_vector_type(4))) int i32x4;
typedef __attribute__((ext_vector_type(16))) int i32x16;

struct __align__(8) bf4 { __hip_bfloat16 h[4]; };

__device__ __forceinline__ float bf2f(short s) {
  union { uint32_t u; float f; } c;
  c.u = ((uint32_t)(uint16_t)s) << 16;
  return c.f;
}
__device__ __forceinline__ int q8(float f) {
  int v = __float2int_rn(f * 32.f);
  return v > 127 ? 127 : (v < -127 ? -127 : v);
}

// async global -> LDS, 16B/lane. LDS dest = wave-uniform base + lane*16.
__device__ __forceinline__ void gload16(const void* g, void* l) {
  __builtin_amdgcn_global_load_lds(
      (const __attribute__((address_space(1))) void*)g,
      (__attribute__((address_space(3))) void*)l, 16, 0, 0);
}

#define BAR() __builtin_amdgcn_s_barrier()
#define WAIT_LGKM0()                                         \
  do {                                                       \
    asm volatile("s_waitcnt lgkmcnt(0)" ::: "memory");       \
    __builtin_amdgcn_sched_barrier(0);                       \
  } while (0)
#define WAIT_VM0()                                           \
  do {                                                       \
    asm volatile("s_waitcnt vmcnt(0)" ::: "memory");         \
  } while (0)

// ---------------------------------------------------------------------------
// bf16 256x256 8-wave GEMM (round-9 structure, TP pairing). Used for Mt and Y.
// OD=0: bf16 OUT[Brow][Arow] j-packed. OD=1: int8 OUT (round(32*val), clamp).
template <int TP, int OD>
__global__ __launch_bounds__(512, 2)
void gemmT_kernel(const __hip_bfloat16* __restrict__ Aall,
                  const __hip_bfloat16* __restrict__ Ball,
                  void* __restrict__ OUTv, int ldo) {
  __shared__ __align__(16) char smem[131072];
  const int t = threadIdx.x, lane = t & 63, wid = t >> 6;
  const int wm = wid >> 2, wn = wid & 3;
  const int g = lane >> 4, l15 = lane & 15, l7 = lane & 7;

  const int at2base = blockIdx.x * TP;
  const int bt2 = blockIdx.y;
  const __hip_bfloat16* Bb = Ball + (size_t)bt2 * 256 * DMODEL;
  auto Aof = [&](int tp) { return Aall + (size_t)(at2base + tp) * 256 * DMODEL; };

  const int srl = t >> 3;
  const int sc8 = (t & 7) ^ (srl & 7);
  const int pc8[2] = {g ^ l7, (4 + g) ^ l7};

  auto stage_mat = [&](const __hip_bfloat16* gs, char* dst, int kt) {
#pragma unroll
    for (int it = 0; it < 4; ++it)
      gload16(gs + (size_t)(it * 64 + srl) * DMODEL + kt * 64 + sc8 * 8,
              dst + it * 8192 + wid * 1024);
  };

  f32x4 acc[8][4];
#pragma unroll
  for (int m = 0; m < 8; ++m)
#pragma unroll
    for (int n = 0; n < 4; ++n) acc[m][n] = (f32x4){0.f, 0.f, 0.f, 0.f};
  short8 afr[2][4], bfr[2][2][2];

#define LDA_Q(MH)                                                           \
  { _Pragma("unroll") for (int m = 0; m < 4; ++m) {                         \
      const int row = wm * 128 + ((MH) * 4 + m) * 16 + l15;                 \
      afr[0][m] = *(const short8*)(At + row * 128 + pc8[0] * 16);           \
      afr[1][m] = *(const short8*)(At + row * 128 + pc8[1] * 16);           \
    } }
#define LDB_Q(NH)                                                           \
  { _Pragma("unroll") for (int n = 0; n < 2; ++n) {                         \
      const int row = wn * 64 + ((NH) * 2 + n) * 16 + l15;                  \
      bfr[NH][0][n] = *(const short8*)(Bt + row * 128 + pc8[0] * 16);       \
      bfr[NH][1][n] = *(const short8*)(Bt + row * 128 + pc8[1] * 16);       \
    } }
#define MFMA_Q(MH, NH)                                                      \
  { __builtin_amdgcn_s_setprio(1);                                          \
    _Pragma("unroll") for (int kk = 0; kk < 2; ++kk)                        \
    _Pragma("unroll") for (int m = 0; m < 4; ++m)                           \
    _Pragma("unroll") for (int n = 0; n < 2; ++n)                           \
      acc[(MH)*4+m][(NH)*2+n] = __builtin_amdgcn_mfma_f32_16x16x32_bf16(    \
          afr[kk][m], bfr[NH][kk][n], acc[(MH)*4+m][(NH)*2+n], 0, 0, 0);    \
    __builtin_amdgcn_s_setprio(0); }

  auto EPI = [&](int at2) {
    const size_t orow0 = (size_t)bt2 * 256 + wn * 64 + l15;
    const int ocol0 = at2 * 256 + wm * 128 + g * 4;
    if constexpr (OD == 0) {
      __hip_bfloat16* OUT = (__hip_bfloat16*)OUTv;
#pragma unroll
      for (int mi = 0; mi < 8; ++mi)
#pragma unroll
        for (int ni = 0; ni < 4; ++ni) {
          bf4 pk;
#pragma unroll
          for (int j = 0; j < 4; ++j) pk.h[j] = __float2bfloat16(acc[mi][ni][j]);
          *(bf4*)(OUT + (orow0 + ni * 16) * ldo + ocol0 + mi * 16) = pk;
        }
    } else {
      uint8_t* O8 = (uint8_t*)OUTv;
#pragma unroll
      for (int mi = 0; mi < 8; ++mi)
#pragma unroll
        for (int ni = 0; ni < 4; ++ni) {
          uint32_t pk = 0;
#pragma unroll
          for (int j = 0; j < 4; ++j)
            pk |= (uint32_t)(q8(acc[mi][ni][j]) & 0xff) << (8 * j);
          *(uint32_t*)(O8 + (orow0 + ni * 16) * (size_t)ldo + ocol0 + mi * 16) = pk;
        }
    }
#pragma unroll
    for (int m = 0; m < 8; ++m)
#pragma unroll
      for (int n = 0; n < 4; ++n) acc[m][n] = (f32x4){0.f, 0.f, 0.f, 0.f};
  };

  stage_mat(Aof(0), smem, 0);
  stage_mat(Bb, smem + 32768, 0);
  WAIT_VM0();
  BAR();

  const int NI = 16 * TP;
#pragma unroll 1
  for (int ii = 0; ii < NI; ++ii) {
    const int p = ii & 1;
    const char* At = smem + (p << 16);
    const char* Bt = smem + 32768 + (p << 16);
    char* An = smem + ((p ^ 1) << 16);
    char* Bn = smem + 32768 + ((p ^ 1) << 16);
    const int kn = (ii + 1) & 15;
    LDA_Q(0) LDB_Q(0)
    if (ii + 1 < NI) stage_mat(Aof((ii + 1) >> 4), An, kn);
    BAR(); WAIT_LGKM0(); MFMA_Q(0, 0) BAR();
    LDB_Q(1)
    if (ii + 1 < NI) stage_mat(Bb, Bn, kn);
    BAR(); WAIT_LGKM0(); MFMA_Q(0, 1) BAR();
    LDA_Q(1)
    BAR(); WAIT_LGKM0(); MFMA_Q(1, 0) BAR();
    MFMA_Q(1, 1)
    WAIT_VM0();
    if ((ii & 15) == 15) EPI(at2base + (ii >> 4));
    BAR();
  }
#undef LDA_Q
#undef LDB_Q
#undef MFMA_Q
}

// ---------------------------------------------------------------------------
// passA int8: S^T = x8i · Y8i^T via mfma_i32_32x32x32_i8 (2x bf16 rate).
// K-step = 128 bytes (32KB tiles, 8 K-steps), TP=4 k-tile pairing.
// E8[k][q] = fp8(exp(s_int*KSC + vb'[k])); Zpart[cb][at2][q].
// grid (16 = qt&7 + 8*group, nb), 512 thr.
__global__ __launch_bounds__(512, 2)
void passA_i8_kernel(const uint8_t* __restrict__ x8,
                     const uint8_t* __restrict__ y8,
                     uint8_t* __restrict__ E8,
                     const float* __restrict__ vball,
                     float* __restrict__ Zpart, int b0) {
  __shared__ __align__(16) char smem[131072 + 2048];
  const int t = threadIdx.x, lane = t & 63, wid = t >> 6;
  const int wm = wid >> 2, wn = wid & 3;
  const int l31 = lane & 31, half = lane >> 5, l7 = lane & 7;

  const int cb = blockIdx.y, b = b0 + cb;
  const int bt2 = blockIdx.x & 7;              // q-tile
  const int at2base = (blockIdx.x >> 3) * 4;   // k-tile group (TP=4)
  const uint8_t* Bb = y8 + ((size_t)b * SEQ + bt2 * 256) * DMODEL;
  const uint8_t* Abatch = x8 + (size_t)b * SEQ * DMODEL;
  auto Aof = [&](int tp) { return Abatch + (size_t)(at2base + tp) * 256 * DMODEL; };

  const int srl = t >> 3;
  const int sc8 = (t & 7) ^ (srl & 7);
  int pcI[4];
#pragma unroll
  for (int ks = 0; ks < 4; ++ks) pcI[ks] = ((ks * 2 + half) ^ l7) * 16;

  auto stage8 = [&](const uint8_t* gs, char* dst, int kt) {
#pragma unroll
    for (int it = 0; it < 4; ++it)
      gload16(gs + (size_t)(it * 64 + srl) * DMODEL + kt * 128 + sc8 * 16,
              dst + it * 8192 + wid * 1024);
  };

  i32x16 acci[4][2];
#pragma unroll
  for (int m = 0; m < 4; ++m)
#pragma unroll
    for (int n = 0; n < 2; ++n)
#pragma unroll
      for (int r = 0; r < 16; ++r) acci[m][n][r] = 0;
  i32x4 afr[2][4], bfr[2][4];

  const int rowA0 = wm * 128 + l31;   // + m*32
  const int rowB0 = wn * 64 + l31;    // + n*32

#define LDA_I(MH)                                                           \
  { _Pragma("unroll") for (int mm = 0; mm < 2; ++mm) {                      \
      const int rb = (rowA0 + ((MH) * 2 + mm) * 32) * 128;                  \
      _Pragma("unroll") for (int ks = 0; ks < 4; ++ks)                      \
        afr[mm][ks] = *(const i32x4*)(At + rb + pcI[ks]);                   \
    } }
#define LDB_I(NH)                                                           \
  { const int rb = (rowB0 + (NH) * 32) * 128;                               \
    _Pragma("unroll") for (int ks = 0; ks < 4; ++ks)                        \
      bfr[NH][ks] = *(const i32x4*)(Bt + rb + pcI[ks]); }
#define MFMA_I(MH, NH)                                                      \
  { __builtin_amdgcn_s_setprio(1);                                          \
    _Pragma("unroll") for (int ks = 0; ks < 4; ++ks)                        \
    _Pragma("unroll") for (int mm = 0; mm < 2; ++mm)                        \
      acci[(MH)*2+mm][NH] = __builtin_amdgcn_mfma_i32_32x32x32_i8(          \
          afr[mm][ks], bfr[NH][ks], acci[(MH)*2+mm][NH], 0, 0, 0);          \
    __builtin_amdgcn_s_setprio(0); }

  auto EPI = [&](int at2) {
    float zc[2] = {0.f, 0.f};
    const int qcol0 = bt2 * 256 + wn * 64 + l31;
#pragma unroll
    for (int m = 0; m < 4; ++m) {
      const int krow_base = at2 * 256 + wm * 128 + m * 32 + 4 * half;
      float4 vv[4];
#pragma unroll
      for (int gg = 0; gg < 4; ++gg)
        vv[gg] = *(const float4*)&vball[(size_t)b * SEQ + krow_base + 8 * gg];
#pragma unroll
      for (int n = 0; n < 2; ++n) {
        const int qcol = qcol0 + n * 32;
#pragma unroll
        for (int r = 0; r < 16; r += 2) {
          const float vj0 = ((const float*)&vv[r >> 2])[r & 3];
          const float vj1 = ((const float*)&vv[r >> 2])[(r + 1) & 3];
          const float e0 = __expf(fmaf((float)acci[m][n][r], KSC, vj0));
          const float e1 = __expf(fmaf((float)acci[m][n][r + 1], KSC, vj1));
          zc[n] += e0 + e1;
          const unsigned p = __builtin_amdgcn_cvt_pk_fp8_f32(e0, e1, 0, false);
          const int krow = krow_base + (r & 3) + 8 * (r >> 2);
          uint8_t* ad = E8 + ((size_t)cb * SEQ + krow) * (size_t)SEQ + qcol;
          ad[0] = (uint8_t)p;
          ad[SEQ] = (uint8_t)(p >> 8);
        }
      }
    }
#pragma unroll
    for (int n = 0; n < 2; ++n) {
      float v = zc[n];
      v += __shfl_xor(v, 32);
      zc[n] = v;
    }
    float* red = (float*)(smem + 131072);
    if (lane < 32) {
#pragma unroll
      for (int n = 0; n < 2; ++n)
        red[wm * 256 + wn * 64 + n * 32 + l31] = zc[n];
    }
    __syncthreads();
    if (t < 256)
      Zpart[((size_t)cb * 8 + at2) * SEQ + bt2 * 256 + t] = red[t] + red[256 + t];
#pragma unroll
    for (int m = 0; m < 4; ++m)
#pragma unroll
      for (int n = 0; n < 2; ++n)
#pragma unroll
        for (int r = 0; r < 16; ++r) acci[m][n][r] = 0;
  };

  // prologue
  stage8(Aof(0), smem, 0);
  stage8(Bb, smem + 32768, 0);
  WAIT_VM0();
  BAR();

  const int NI = 32;  // 8 K-steps x TP=4
#pragma unroll 1
  for (int ii = 0; ii < NI; ++ii) {
    const int p = ii & 1;
    const char* At = smem + (p << 16);
    const char* Bt = smem + 32768 + (p << 16);
    char* An = smem + ((p ^ 1) << 16);
    char* Bn = smem + 32768 + ((p ^ 1) << 16);
    const int kn = (ii + 1) & 7;
    LDA_I(0) LDB_I(0)
    if (ii + 1 < NI) stage8(Aof((ii + 1) >> 3), An, kn);
    BAR(); WAIT_LGKM0(); MFMA_I(0, 0) BAR();
    LDB_I(1)
    if (ii + 1 < NI) stage8(Bb, Bn, kn);
    BAR(); WAIT_LGKM0(); MFMA_I(0, 1) BAR();
    LDA_I(1)
    BAR(); WAIT_LGKM0(); MFMA_I(1, 0) BAR();
    MFMA_I(1, 1)
    WAIT_VM0();
    if ((ii & 7) == 7) EPI(at2base + (ii >> 3));
    BAR();
  }
#undef LDA_I
#undef LDB_I
#undef MFMA_I
}

// ---------------------------------------------------------------------------
// fp32 [DMODEL][DMODEL] -> bf16 transposed
__global__ void transpose_cvt_kernel(const float* __restrict__ in,
                                     __hip_bfloat16* __restrict__ outp) {
  __shared__ float tile[32][33];
  const int bx = blockIdx.x, by = blockIdx.y;
  const int tx = threadIdx.x & 31, ty = threadIdx.x >> 5;
#pragma unroll
  for (int r = 0; r < 32; r += 8)
    tile[ty + r][tx] = in[(size_t)(by * 32 + ty + r) * DMODEL + bx * 32 + tx];
  __syncthreads();
#pragma unroll
  for (int r = 0; r < 32; r += 8)
    outp[(size_t)(bx * 32 + ty + r) * DMODEL + by * 32 + tx] =
        __float2bfloat16(tile[tx][ty + r]);
}

// t2[d] = sum_e Wk[e][d]*bq[e]
__global__ __launch_bounds__(256)
void prep_t2_kernel(const __hip_bfloat16* __restrict__ WkT,
                    const float* __restrict__ bq, float* __restrict__ t2) {
  const int wave = threadIdx.x >> 6, lane = threadIdx.x & 63;
  const int d = blockIdx.x * 4 + wave;
  const short8* kr = (const short8*)(WkT + (size_t)d * DMODEL);
  float a2 = 0.f;
#pragma unroll
  for (int h = 0; h < 2; ++h) {
    const short8 kv = kr[lane * 2 + h];
    const int e0 = lane * 16 + h * 8;
#pragma unroll
    for (int i = 0; i < 8; ++i) a2 += bf2f(kv[i]) * bq[e0 + i];
  }
  a2 += __shfl_down(a2, 32); a2 += __shfl_down(a2, 16); a2 += __shfl_down(a2, 8);
  a2 += __shfl_down(a2, 4);  a2 += __shfl_down(a2, 2);  a2 += __shfl_down(a2, 1);
  if (lane == 0) t2[d] = a2;
}

// fused: x -> x_bf + x8i (round(32x)) + vb'
__global__ __launch_bounds__(256)
void cvtv_kernel(const float* __restrict__ x, const float* __restrict__ t2,
                 const int* __restrict__ mask,
                 __hip_bfloat16* __restrict__ x_bf, uint8_t* __restrict__ x8,
                 float* __restrict__ vb) {
  const int wave = threadIdx.x >> 6, lane = threadIdx.x & 63;
  const size_t row = (size_t)blockIdx.x * 4 + wave;
  const float* xr = x + row * DMODEL;
  float a2 = 0.f;
#pragma unroll
  for (int p = 0; p < 4; ++p) {
    const int d = p * 256 + lane * 4;
    const float4 xv = *(const float4*)(xr + d);
    const float4 tv = *(const float4*)(t2 + d);
    a2 += xv.x * tv.x + xv.y * tv.y + xv.z * tv.z + xv.w * tv.w;
    bf4 pk;
    pk.h[0] = __float2bfloat16(xv.x); pk.h[1] = __float2bfloat16(xv.y);
    pk.h[2] = __float2bfloat16(xv.z); pk.h[3] = __float2bfloat16(xv.w);
    *(bf4*)(x_bf + row * DMODEL + d) = pk;
    uint32_t qp = (uint32_t)(q8(xv.x) & 0xff) | ((uint32_t)(q8(xv.y) & 0xff) << 8) |
                  ((uint32_t)(q8(xv.z) & 0xff) << 16) |
                  ((uint32_t)(q8(xv.w) & 0xff) << 24);
    *(uint32_t*)(x8 + row * DMODEL + d) = qp;
  }
  a2 += __shfl_down(a2, 32); a2 += __shfl_down(a2, 16); a2 += __shfl_down(a2, 8);
  a2 += __shfl_down(a2, 4);  a2 += __shfl_down(a2, 2);  a2 += __shfl_down(a2, 1);
  if (lane == 0)
    vb[row] = mask[row] ? fmaf(a2, CS, -NEG4LN2) : -1e30f;
}

// rZ[cb][q] = 1 / sum Zpart  (0 if empty)
__global__ void zinv_kernel(const float* __restrict__ Zpart,
                            float* __restrict__ rZ, int n) {
  const int idx = blockIdx.x * 256 + threadIdx.x;
  if (idx >= n) return;
  const int cb = idx >> 11, q = idx & (SEQ - 1);
  float z = 0.f;
#pragma unroll
  for (int kt = 0; kt < 8; ++kt)
    z += Zpart[((size_t)cb * 8 + kt) * SEQ + q];
  rZ[(size_t)cb * SEQ + q] = (z > 0.f) ? (1.f / z) : 0.f;
}

// passB: w[k] = sum_q E8[k][q] * rZ[q]
__global__ __launch_bounds__(256)
void passB_kernel(const uint8_t* __restrict__ E8,
                  const float* __restrict__ rZ,
                  float* __restrict__ wout) {
  const int t = threadIdx.x, lane = t & 63, wave = t >> 6;
  const int cb = blockIdx.y;
  float4 rzv[4][2];
#pragma unroll
  for (int it = 0; it < 4; ++it) {
    const float4* p = (const float4*)(rZ + (size_t)cb * SEQ + it * 512 + lane * 8);
    rzv[it][0] = p[0];
    rzv[it][1] = p[1];
  }
  const int kbase = blockIdx.x * 16 + wave * 4;
#pragma unroll
  for (int r = 0; r < 4; ++r) {
    const int k = kbase + r;
    const uint2* Ep = (const uint2*)(E8 + ((size_t)cb * SEQ + k) * SEQ);
    float s = 0.f;
#pragma unroll
    for (int it = 0; it < 4; ++it) {
      const uint2 v = Ep[it * 64 + lane];
      const float* rz = (const float*)&rzv[it][0];
      s += __builtin_amdgcn_cvt_f32_fp8(v.x, 0) * rz[0];
      s += __builtin_amdgcn_cvt_f32_fp8(v.x, 1) * rz[1];
      s += __builtin_amdgcn_cvt_f32_fp8(v.x, 2) * rz[2];
      s += __builtin_amdgcn_cvt_f32_fp8(v.x, 3) * rz[3];
      s += __builtin_amdgcn_cvt_f32_fp8(v.y, 0) * rz[4];
      s += __builtin_amdgcn_cvt_f32_fp8(v.y, 1) * rz[5];
      s += __builtin_amdgcn_cvt_f32_fp8(v.y, 2) * rz[6];
      s += __builtin_amdgcn_cvt_f32_fp8(v.y, 3) * rz[7];
    }
    s += __shfl_down(s, 32); s += __shfl_down(s, 16); s += __shfl_down(s, 8);
    s += __shfl_down(s, 4);  s += __shfl_down(s, 2);  s += __shfl_down(s, 1);
    if (lane == 0) wout[(size_t)cb * SEQ + k] = s;
  }
}

// sumw_all[b] = sum_k w[k]
__global__ void sumw_kernel(const float* __restrict__ w,
                            float* __restrict__ sumw_all, int b0) {
  __shared__ float sred[4];
  const int t = threadIdx.x, lane = t & 63, wave = t >> 6;
  const int cb = blockIdx.x;
  float v = 0.f;
  for (int k = t; k < SEQ; k += 256) v += w[(size_t)cb * SEQ + k];
  v += __shfl_down(v, 32); v += __shfl_down(v, 16); v += __shfl_down(v, 8);
  v += __shfl_down(v, 4);  v += __shfl_down(v, 2);  v += __shfl_down(v, 1);
  if (lane == 0) sred[wave] = v;
  __syncthreads();
  if (t == 0) sumw_all[b0 + cb] = sred[0] + sred[1] + sred[2] + sred[3];
}

// wxp[kq][b][d] = sum_{k in chunk kq} w[k] * x_bf[b][k][d]
__global__ void wxpart_kernel(const __hip_bfloat16* __restrict__ x_bf,
                              const float* __restrict__ w,
                              float* __restrict__ wxp, int b0) {
  const int dt = blockIdx.x, cb = blockIdx.y, kq = blockIdx.z;
  const int b = b0 + cb;
  const int dp = dt * 256 + threadIdx.x;
  const __hip_bfloat16* xb =
      x_bf + ((size_t)b * SEQ + (size_t)kq * (SEQ / KSPLIT)) * DMODEL;
  const float* wb = w + (size_t)cb * SEQ + (size_t)kq * (SEQ / KSPLIT);
  float a0 = 0.f, a1 = 0.f;
#pragma unroll 4
  for (int k = 0; k < SEQ / KSPLIT; ++k) {
    const float wk = wb[k];
    const uint32_t pv = *(const uint32_t*)(xb + (size_t)k * DMODEL + dp * 2);
    a0 += wk * bf2f((short)(pv & 0xffff));
    a1 += wk * bf2f((short)(pv >> 16));
  }
  float2* o = (float2*)&wxp[((size_t)kq * NBATCH + b) * DMODEL + dp * 2];
  *o = make_float2(a0, a1);
}

// out[b][e] = ( sum_d (sum_kq wxp) * Wv[e][d] + sumw[b]*bv[e] ) / SEQ
__global__ void final_kernel(const float* __restrict__ wxp,
                             const float* __restrict__ sumw_all,
                             const float* __restrict__ Wv,
                             const float* __restrict__ bv,
                             float* __restrict__ out) {
  const int b = blockIdx.y, eg = blockIdx.x;
  const int wave = threadIdx.x >> 6, lane = threadIdx.x & 63;
  const int e = eg * 4 + wave;
  float acc = 0.f;
  for (int d = lane; d < DMODEL; d += 64) {
    float wx = 0.f;
#pragma unroll
    for (int kq = 0; kq < KSPLIT; ++kq)
      wx += wxp[((size_t)kq * NBATCH + b) * DMODEL + d];
    acc += wx * Wv[(size_t)e * DMODEL + d];
  }
  acc += __shfl_down(acc, 32); acc += __shfl_down(acc, 16);
  acc += __shfl_down(acc, 8);  acc += __shfl_down(acc, 4);
  acc += __shfl_down(acc, 2);  acc += __shfl_down(acc, 1);
  if (lane == 0)
    out[(size_t)b * DMODEL + e] =
        (acc + sumw_all[b] * bv[e]) * (1.f / (float)SEQ);
}

// ---------------------------------------------------------------------------
extern "C" void kernel_launch(void* const* d_in, const int* in_sizes, int n_in,
                              void* d_out, int out_size, void* d_ws, size_t ws_size,
                              hipStream_t stream) {
  const float* x  = (const float*)d_in[0];
  const int* mask = (const int*)d_in[1];
  const float* Wq = (const float*)d_in[2];
  const float* bq = (const float*)d_in[3];
  const float* Wk = (const float*)d_in[4];
  const float* bk = (const float*)d_in[5];
  const float* Wv = (const float*)d_in[6];
  const float* bv = (const float*)d_in[7];
  float* out = (float*)d_out;
  (void)bk;

  char* ws = (char*)d_ws;
  size_t off = 0;
  auto alloc = [&](size_t bytes) -> void* {
    void* p = ws + off;
    off += (bytes + 255) & ~(size_t)255;
    return p;
  };
  // ---- persistent ----
  __hip_bfloat16* Mt_bf  = (__hip_bfloat16*)alloc((size_t)DMODEL * DMODEL * 2);
  __hip_bfloat16* WqT_bf = (__hip_bfloat16*)alloc((size_t)DMODEL * DMODEL * 2);
  __hip_bfloat16* WkT_bf = (__hip_bfloat16*)alloc((size_t)DMODEL * DMODEL * 2);
  float* wxp      = (float*)alloc((size_t)KSPLIT * NBATCH * DMODEL * 4);
  float* sumw_all = (float*)alloc((size_t)NBATCH * 4);
  float* t2       = (float*)alloc((size_t)DMODEL * 4);
  __hip_bfloat16* x_bf = (__hip_bfloat16*)alloc((size_t)NBATCH * SEQ * DMODEL * 2);
  uint8_t* x8i = (uint8_t*)alloc((size_t)NBATCH * SEQ * DMODEL);
  uint8_t* Y8i = (uint8_t*)alloc((size_t)NBATCH * SEQ * DMODEL);
  float* vb = (float*)alloc((size_t)NBATCH * SEQ * 4);
  const size_t fixed = off;

  // ---- per-chunk ----
  const size_t per_batch = (size_t)SEQ * SEQ * 1       // E (fp8)
                         + (size_t)8 * SEQ * 4         // Zpart
                         + (size_t)2 * SEQ * 4 + 8 * 256;
  long avail = (long)ws_size - (long)fixed;
  int NB = (int)(avail / (long)per_batch);
  if (NB < 1) NB = 1;
  if (NB > NBATCH) NB = NBATCH;
  while (NBATCH % NB) --NB;
  uint8_t* Ebuf = (uint8_t*)alloc((size_t)NB * SEQ * SEQ);
  float* Zpart = (float*)alloc((size_t)NB * 8 * SEQ * 4);
  float* rZ    = (float*)alloc((size_t)NB * SEQ * 4);
  float* wbuf  = (float*)alloc((size_t)NB * SEQ * 4);

  // ---- prep ----
  transpose_cvt_kernel<<<dim3(32, 32), dim3(256), 0, stream>>>(Wq, WqT_bf);
  transpose_cvt_kernel<<<dim3(32, 32), dim3(256), 0, stream>>>(Wk, WkT_bf);
  // Mt[d'][d] = sum_e WkT[d'][e]*WqT[d][e]   (bf16 out)
  gemmT_kernel<1, 0><<<dim3(4, 4), dim3(512), 0, stream>>>(
      WqT_bf, WkT_bf, Mt_bf, DMODEL);
  prep_t2_kernel<<<dim3(256), dim3(256), 0, stream>>>(WkT_bf, bq, t2);
  cvtv_kernel<<<dim3(NBATCH * SEQ / 4), dim3(256), 0, stream>>>(
      x, t2, mask, x_bf, x8i, vb);
  // Y8i[q][d'] = round(32 * sum_d x[q][d]*Mt[d'][d])  (int8 out)
  gemmT_kernel<2, 1><<<dim3(2, NBATCH * 8), dim3(512), 0, stream>>>(
      Mt_bf, x_bf, Y8i, DMODEL);

  for (int b0 = 0; b0 < NBATCH; b0 += NB) {
    const int nb = NB;
    passA_i8_kernel<<<dim3(16, nb), dim3(512), 0, stream>>>(
        x8i, Y8i, Ebuf, vb, Zpart, b0);
    zinv_kernel<<<dim3((nb * SEQ + 255) / 256), dim3(256), 0, stream>>>(
        Zpart, rZ, nb * SEQ);
    passB_kernel<<<dim3(SEQ / 16, nb), dim3(256), 0, stream>>>(Ebuf, rZ, wbuf);
    sumw_kernel<<<dim3(nb), dim3(256), 0, stream>>>(wbuf, sumw_all, b0);
    wxpart_kernel<<<dim3(DMODEL / 512, nb, KSPLIT), dim3(256), 0, stream>>>(
        x_bf, wbuf, wxp, b0);
  }
  final_kernel<<<dim3(DMODEL / 4, NBATCH), dim3(256), 0, stream>>>(
      wxp, sumw_all, Wv, bv, out);
}

// Round 12
// 274.313 us; speedup vs baseline: 1.8642x; 1.1716x over previous
//
#include <hip/hip_runtime.h>
#include <hip/hip_bf16.h>
#include <stdint.h>

#define NBATCH 16
#define SEQ    2048
#define DMODEL 1024
#define KSPLIT 16

// exp((s+v)/32) * 2^-4 ; s from i8 GEMM as s_int = 1024*s_raw
#define CS      0.03125f
#define KSC     3.0517578125e-5f   // CS/1024
#define NEG4LN2 2.772588722f

typedef __attribute__((ext_vector_type(8))) short short8;
typedef __attribute__((ext_vector_type(4))) float f32x4;
typedef __attribute__((ext_vector_type(4))) int i32x4;
typedef __attribute__((ext_vector_type(16))) int i32x16;

struct __align__(8) bf4 { __hip_bfloat16 h[4]; };

__device__ __forceinline__ float bf2f(short s) {
  union { uint32_t u; float f; } c;
  c.u = ((uint32_t)(uint16_t)s) << 16;
  return c.f;
}
__device__ __forceinline__ int qs8(float f, float sc) {
  int v = __float2int_rn(f * sc);
  return v > 127 ? 127 : (v < -127 ? -127 : v);
}

// async global -> LDS, 16B/lane. LDS dest = wave-uniform base + lane*16.
__device__ __forceinline__ void gload16(const void* g, void* l) {
  __builtin_amdgcn_global_load_lds(
      (const __attribute__((address_space(1))) void*)g,
      (__attribute__((address_space(3))) void*)l, 16, 0, 0);
}

#define BAR() __builtin_amdgcn_s_barrier()
#define WAIT_LGKM0()                                         \
  do {                                                       \
    asm volatile("s_waitcnt lgkmcnt(0)" ::: "memory");       \
    __builtin_amdgcn_sched_barrier(0);                       \
  } while (0)
#define WAIT_VM0()                                           \
  do {                                                       \
    asm volatile("s_waitcnt vmcnt(0)" ::: "memory");         \
  } while (0)

// ---------------------------------------------------------------------------
// bf16 256x256 8-wave GEMM (round-9 structure). Only used for Mt8:
// OUT int8[Brow][Arow] = clamp(round(1024 * sum_e A[Arow][e]*B[Brow][e])).
template <int TP>
__global__ __launch_bounds__(512, 2)
void gemmT_kernel(const __hip_bfloat16* __restrict__ Aall,
                  const __hip_bfloat16* __restrict__ Ball,
                  uint8_t* __restrict__ O8, int ldo) {
  __shared__ __align__(16) char smem[131072];
  const int t = threadIdx.x, lane = t & 63, wid = t >> 6;
  const int wm = wid >> 2, wn = wid & 3;
  const int g = lane >> 4, l15 = lane & 15, l7 = lane & 7;

  const int at2base = blockIdx.x * TP;
  const int bt2 = blockIdx.y;
  const __hip_bfloat16* Bb = Ball + (size_t)bt2 * 256 * DMODEL;
  auto Aof = [&](int tp) { return Aall + (size_t)(at2base + tp) * 256 * DMODEL; };

  const int srl = t >> 3;
  const int sc8 = (t & 7) ^ (srl & 7);
  const int pc8[2] = {g ^ l7, (4 + g) ^ l7};

  auto stage_mat = [&](const __hip_bfloat16* gs, char* dst, int kt) {
#pragma unroll
    for (int it = 0; it < 4; ++it)
      gload16(gs + (size_t)(it * 64 + srl) * DMODEL + kt * 64 + sc8 * 8,
              dst + it * 8192 + wid * 1024);
  };

  f32x4 acc[8][4];
#pragma unroll
  for (int m = 0; m < 8; ++m)
#pragma unroll
    for (int n = 0; n < 4; ++n) acc[m][n] = (f32x4){0.f, 0.f, 0.f, 0.f};
  short8 afr[2][4], bfr[2][2][2];

#define LDA_Q(MH)                                                           \
  { _Pragma("unroll") for (int m = 0; m < 4; ++m) {                         \
      const int row = wm * 128 + ((MH) * 4 + m) * 16 + l15;                 \
      afr[0][m] = *(const short8*)(At + row * 128 + pc8[0] * 16);           \
      afr[1][m] = *(const short8*)(At + row * 128 + pc8[1] * 16);           \
    } }
#define LDB_Q(NH)                                                           \
  { _Pragma("unroll") for (int n = 0; n < 2; ++n) {                         \
      const int row = wn * 64 + ((NH) * 2 + n) * 16 + l15;                  \
      bfr[NH][0][n] = *(const short8*)(Bt + row * 128 + pc8[0] * 16);       \
      bfr[NH][1][n] = *(const short8*)(Bt + row * 128 + pc8[1] * 16);       \
    } }
#define MFMA_Q(MH, NH)                                                      \
  { __builtin_amdgcn_s_setprio(1);                                          \
    _Pragma("unroll") for (int kk = 0; kk < 2; ++kk)                        \
    _Pragma("unroll") for (int m = 0; m < 4; ++m)                           \
    _Pragma("unroll") for (int n = 0; n < 2; ++n)                           \
      acc[(MH)*4+m][(NH)*2+n] = __builtin_amdgcn_mfma_f32_16x16x32_bf16(    \
          afr[kk][m], bfr[NH][kk][n], acc[(MH)*4+m][(NH)*2+n], 0, 0, 0);    \
    __builtin_amdgcn_s_setprio(0); }

  auto EPI = [&](int at2) {
    const size_t orow0 = (size_t)bt2 * 256 + wn * 64 + l15;
    const int ocol0 = at2 * 256 + wm * 128 + g * 4;
#pragma unroll
    for (int mi = 0; mi < 8; ++mi)
#pragma unroll
      for (int ni = 0; ni < 4; ++ni) {
        uint32_t pk = 0;
#pragma unroll
        for (int j = 0; j < 4; ++j)
          pk |= (uint32_t)(qs8(acc[mi][ni][j], 1024.f) & 0xff) << (8 * j);
        *(uint32_t*)(O8 + (orow0 + ni * 16) * (size_t)ldo + ocol0 + mi * 16) = pk;
      }
#pragma unroll
    for (int m = 0; m < 8; ++m)
#pragma unroll
      for (int n = 0; n < 4; ++n) acc[m][n] = (f32x4){0.f, 0.f, 0.f, 0.f};
  };

  stage_mat(Aof(0), smem, 0);
  stage_mat(Bb, smem + 32768, 0);
  WAIT_VM0();
  BAR();

  const int NI = 16 * TP;
#pragma unroll 1
  for (int ii = 0; ii < NI; ++ii) {
    const int p = ii & 1;
    const char* At = smem + (p << 16);
    const char* Bt = smem + 32768 + (p << 16);
    char* An = smem + ((p ^ 1) << 16);
    char* Bn = smem + 32768 + ((p ^ 1) << 16);
    const int kn = (ii + 1) & 15;
    LDA_Q(0) LDB_Q(0)
    if (ii + 1 < NI) stage_mat(Aof((ii + 1) >> 4), An, kn);
    BAR(); WAIT_LGKM0(); MFMA_Q(0, 0) BAR();
    LDB_Q(1)
    if (ii + 1 < NI) stage_mat(Bb, Bn, kn);
    BAR(); WAIT_LGKM0(); MFMA_Q(0, 1) BAR();
    LDA_Q(1)
    BAR(); WAIT_LGKM0(); MFMA_Q(1, 0) BAR();
    MFMA_Q(1, 1)
    WAIT_VM0();
    if ((ii & 15) == 15) EPI(at2base + (ii >> 4));
    BAR();
  }
#undef LDA_Q
#undef LDB_Q
#undef MFMA_Q
}

// ---------------------------------------------------------------------------
// int8 256x256 8-wave GEMM, K-step 128B, mfma_i32_32x32x32_i8 (round-11 core).
// MODE 0: OUT int8[Arow][Brow] = clamp(round(acc/1024)) (Y = x8.Mt8).
//         grid (ATILES/TP, BTILES); Aall rows = NBATCH*SEQ, Ball rows = 1024.
// MODE 1: passA. A=x8 (k rows), B=Y8 (q rows). E8[k][q] = fp8(exp(acc*KSC+vb'));
//         Zpart. grid (8*(8/TP)... = qt&7 + 8*group, nb).
template <int MODE, int TP>
__global__ __launch_bounds__(512, 2)
void i8gemm_kernel(const uint8_t* __restrict__ Aall,
                   const uint8_t* __restrict__ Ball,
                   uint8_t* __restrict__ OUT8,
                   const float* __restrict__ vball,
                   float* __restrict__ Zpart, int b0) {
  __shared__ __align__(16) char smem[131072 + 2048];
  const int t = threadIdx.x, lane = t & 63, wid = t >> 6;
  const int wm = wid >> 2, wn = wid & 3;
  const int l31 = lane & 31, half = lane >> 5, l7 = lane & 7;

  int at2base, bt2, cb = 0, b = 0;
  const uint8_t *Bb, *Abatch;
  if constexpr (MODE == 0) {
    at2base = blockIdx.x * TP;
    bt2 = blockIdx.y;
    Abatch = Aall;
    Bb = Ball + (size_t)bt2 * 256 * DMODEL;
  } else {
    cb = blockIdx.y; b = b0 + cb;
    bt2 = blockIdx.x & 7;              // q-tile (pins XCD to a Y panel)
    at2base = (blockIdx.x >> 3) * TP;  // k-tile group
    Abatch = Aall + (size_t)b * SEQ * DMODEL;
    Bb = Ball + ((size_t)b * SEQ + bt2 * 256) * DMODEL;
  }
  auto Aof = [&](int tp) { return Abatch + (size_t)(at2base + tp) * 256 * DMODEL; };

  const int srl = t >> 3;
  const int sc8 = (t & 7) ^ (srl & 7);
  int pcI[4];
#pragma unroll
  for (int ks = 0; ks < 4; ++ks) pcI[ks] = ((ks * 2 + half) ^ l7) * 16;

  auto stage8 = [&](const uint8_t* gs, char* dst, int kt) {
#pragma unroll
    for (int it = 0; it < 4; ++it)
      gload16(gs + (size_t)(it * 64 + srl) * DMODEL + kt * 128 + sc8 * 16,
              dst + it * 8192 + wid * 1024);
  };

  i32x16 acci[4][2];
#pragma unroll
  for (int m = 0; m < 4; ++m)
#pragma unroll
    for (int n = 0; n < 2; ++n)
#pragma unroll
      for (int r = 0; r < 16; ++r) acci[m][n][r] = 0;
  i32x4 afr[2][4], bfr[2][4];

  const int rowA0 = wm * 128 + l31;
  const int rowB0 = wn * 64 + l31;

#define LDA_I(MH)                                                           \
  { _Pragma("unroll") for (int mm = 0; mm < 2; ++mm) {                      \
      const int rb = (rowA0 + ((MH) * 2 + mm) * 32) * 128;                  \
      _Pragma("unroll") for (int ks = 0; ks < 4; ++ks)                      \
        afr[mm][ks] = *(const i32x4*)(At + rb + pcI[ks]);                   \
    } }
#define LDB_I(NH)                                                           \
  { const int rb = (rowB0 + (NH) * 32) * 128;                               \
    _Pragma("unroll") for (int ks = 0; ks < 4; ++ks)                        \
      bfr[NH][ks] = *(const i32x4*)(Bt + rb + pcI[ks]); }
#define MFMA_I(MH, NH)                                                      \
  { __builtin_amdgcn_s_setprio(1);                                          \
    _Pragma("unroll") for (int ks = 0; ks < 4; ++ks)                        \
    _Pragma("unroll") for (int mm = 0; mm < 2; ++mm)                        \
      acci[(MH)*2+mm][NH] = __builtin_amdgcn_mfma_i32_32x32x32_i8(          \
          afr[mm][ks], bfr[NH][ks], acci[(MH)*2+mm][NH], 0, 0, 0);          \
    __builtin_amdgcn_s_setprio(0); }

  auto EPI = [&](int at2) {
    if constexpr (MODE == 0) {
      const int bcol0 = bt2 * 256 + wn * 64 + l31;
#pragma unroll
      for (int m = 0; m < 4; ++m) {
        const int arow_base = at2 * 256 + wm * 128 + m * 32 + 4 * half;
#pragma unroll
        for (int n = 0; n < 2; ++n) {
          const int bcol = bcol0 + n * 32;
#pragma unroll
          for (int r = 0; r < 16; ++r) {
            const int arow = arow_base + (r & 3) + 8 * (r >> 2);
            OUT8[(size_t)arow * DMODEL + bcol] =
                (uint8_t)qs8((float)acci[m][n][r], 9.765625e-4f);  // /1024
          }
        }
      }
    } else {
      float zc[2] = {0.f, 0.f};
      const int qcol0 = bt2 * 256 + wn * 64 + l31;
#pragma unroll
      for (int m = 0; m < 4; ++m) {
        const int krow_base = at2 * 256 + wm * 128 + m * 32 + 4 * half;
        float4 vv[4];
#pragma unroll
        for (int gg = 0; gg < 4; ++gg)
          vv[gg] = *(const float4*)&vball[(size_t)b * SEQ + krow_base + 8 * gg];
#pragma unroll
        for (int n = 0; n < 2; ++n) {
          const int qcol = qcol0 + n * 32;
#pragma unroll
          for (int r = 0; r < 16; r += 2) {
            const float vj0 = ((const float*)&vv[r >> 2])[r & 3];
            const float vj1 = ((const float*)&vv[r >> 2])[(r + 1) & 3];
            const float e0 = __expf(fmaf((float)acci[m][n][r], KSC, vj0));
            const float e1 = __expf(fmaf((float)acci[m][n][r + 1], KSC, vj1));
            zc[n] += e0 + e1;
            const unsigned p = __builtin_amdgcn_cvt_pk_fp8_f32(e0, e1, 0, false);
            const int krow = krow_base + (r & 3) + 8 * (r >> 2);
            uint8_t* ad = OUT8 + ((size_t)cb * SEQ + krow) * (size_t)SEQ + qcol;
            ad[0] = (uint8_t)p;
            ad[SEQ] = (uint8_t)(p >> 8);
          }
        }
      }
#pragma unroll
      for (int n = 0; n < 2; ++n) {
        float v = zc[n];
        v += __shfl_xor(v, 32);
        zc[n] = v;
      }
      float* red = (float*)(smem + 131072);
      if (lane < 32) {
#pragma unroll
        for (int n = 0; n < 2; ++n)
          red[wm * 256 + wn * 64 + n * 32 + l31] = zc[n];
      }
      __syncthreads();
      if (t < 256)
        Zpart[((size_t)cb * 8 + at2) * SEQ + bt2 * 256 + t] = red[t] + red[256 + t];
    }
#pragma unroll
    for (int m = 0; m < 4; ++m)
#pragma unroll
      for (int n = 0; n < 2; ++n)
#pragma unroll
        for (int r = 0; r < 16; ++r) acci[m][n][r] = 0;
  };

  stage8(Aof(0), smem, 0);
  stage8(Bb, smem + 32768, 0);
  WAIT_VM0();
  BAR();

  const int NI = 8 * TP;
#pragma unroll 1
  for (int ii = 0; ii < NI; ++ii) {
    const int p = ii & 1;
    const char* At = smem + (p << 16);
    const char* Bt = smem + 32768 + (p << 16);
    char* An = smem + ((p ^ 1) << 16);
    char* Bn = smem + 32768 + ((p ^ 1) << 16);
    const int kn = (ii + 1) & 7;
    LDA_I(0) LDB_I(0)
    if (ii + 1 < NI) stage8(Aof((ii + 1) >> 3), An, kn);
    BAR(); WAIT_LGKM0(); MFMA_I(0, 0) BAR();
    LDB_I(1)
    if (ii + 1 < NI) stage8(Bb, Bn, kn);
    BAR(); WAIT_LGKM0(); MFMA_I(0, 1) BAR();
    LDA_I(1)
    BAR(); WAIT_LGKM0(); MFMA_I(1, 0) BAR();
    MFMA_I(1, 1)
    WAIT_VM0();
    if ((ii & 7) == 7) EPI(at2base + (ii >> 3));
    BAR();
  }
#undef LDA_I
#undef LDB_I
#undef MFMA_I
}

// ---------------------------------------------------------------------------
// fp32 [DMODEL][DMODEL] -> bf16 transposed
__global__ void transpose_cvt_kernel(const float* __restrict__ in,
                                     __hip_bfloat16* __restrict__ outp) {
  __shared__ float tile[32][33];
  const int bx = blockIdx.x, by = blockIdx.y;
  const int tx = threadIdx.x & 31, ty = threadIdx.x >> 5;
#pragma unroll
  for (int r = 0; r < 32; r += 8)
    tile[ty + r][tx] = in[(size_t)(by * 32 + ty + r) * DMODEL + bx * 32 + tx];
  __syncthreads();
#pragma unroll
  for (int r = 0; r < 32; r += 8)
    outp[(size_t)(bx * 32 + ty + r) * DMODEL + by * 32 + tx] =
        __float2bfloat16(tile[tx][ty + r]);
}

// t2[d] = sum_e Wk[e][d]*bq[e]
__global__ __launch_bounds__(256)
void prep_t2_kernel(const __hip_bfloat16* __restrict__ WkT,
                    const float* __restrict__ bq, float* __restrict__ t2) {
  const int wave = threadIdx.x >> 6, lane = threadIdx.x & 63;
  const int d = blockIdx.x * 4 + wave;
  const short8* kr = (const short8*)(WkT + (size_t)d * DMODEL);
  float a2 = 0.f;
#pragma unroll
  for (int h = 0; h < 2; ++h) {
    const short8 kv = kr[lane * 2 + h];
    const int e0 = lane * 16 + h * 8;
#pragma unroll
    for (int i = 0; i < 8; ++i) a2 += bf2f(kv[i]) * bq[e0 + i];
  }
  a2 += __shfl_down(a2, 32); a2 += __shfl_down(a2, 16); a2 += __shfl_down(a2, 8);
  a2 += __shfl_down(a2, 4);  a2 += __shfl_down(a2, 2);  a2 += __shfl_down(a2, 1);
  if (lane == 0) t2[d] = a2;
}

// fused: x -> x8i (round(32x)) + vb'
__global__ __launch_bounds__(256)
void cvtv_kernel(const float* __restrict__ x, const float* __restrict__ t2,
                 const int* __restrict__ mask,
                 uint8_t* __restrict__ x8, float* __restrict__ vb) {
  const int wave = threadIdx.x >> 6, lane = threadIdx.x & 63;
  const size_t row = (size_t)blockIdx.x * 4 + wave;
  const float* xr = x + row * DMODEL;
  float a2 = 0.f;
#pragma unroll
  for (int p = 0; p < 4; ++p) {
    const int d = p * 256 + lane * 4;
    const float4 xv = *(const float4*)(xr + d);
    const float4 tv = *(const float4*)(t2 + d);
    a2 += xv.x * tv.x + xv.y * tv.y + xv.z * tv.z + xv.w * tv.w;
    uint32_t qp = (uint32_t)(qs8(xv.x, 32.f) & 0xff) |
                  ((uint32_t)(qs8(xv.y, 32.f) & 0xff) << 8) |
                  ((uint32_t)(qs8(xv.z, 32.f) & 0xff) << 16) |
                  ((uint32_t)(qs8(xv.w, 32.f) & 0xff) << 24);
    *(uint32_t*)(x8 + row * DMODEL + d) = qp;
  }
  a2 += __shfl_down(a2, 32); a2 += __shfl_down(a2, 16); a2 += __shfl_down(a2, 8);
  a2 += __shfl_down(a2, 4);  a2 += __shfl_down(a2, 2);  a2 += __shfl_down(a2, 1);
  if (lane == 0)
    vb[row] = mask[row] ? fmaf(a2, CS, -NEG4LN2) : -1e30f;
}

// rZ[cb][q] = 1 / sum Zpart  (0 if empty)
__global__ void zinv_kernel(const float* __restrict__ Zpart,
                            float* __restrict__ rZ, int n) {
  const int idx = blockIdx.x * 256 + threadIdx.x;
  if (idx >= n) return;
  const int cb = idx >> 11, q = idx & (SEQ - 1);
  float z = 0.f;
#pragma unroll
  for (int kt = 0; kt < 8; ++kt)
    z += Zpart[((size_t)cb * 8 + kt) * SEQ + q];
  rZ[(size_t)cb * SEQ + q] = (z > 0.f) ? (1.f / z) : 0.f;
}

// passB: w[k] = sum_q E8[k][q] * rZ[q]
__global__ __launch_bounds__(256)
void passB_kernel(const uint8_t* __restrict__ E8,
                  const float* __restrict__ rZ,
                  float* __restrict__ wout) {
  const int t = threadIdx.x, lane = t & 63, wave = t >> 6;
  const int cb = blockIdx.y;
  float4 rzv[4][2];
#pragma unroll
  for (int it = 0; it < 4; ++it) {
    const float4* p = (const float4*)(rZ + (size_t)cb * SEQ + it * 512 + lane * 8);
    rzv[it][0] = p[0];
    rzv[it][1] = p[1];
  }
  const int kbase = blockIdx.x * 16 + wave * 4;
#pragma unroll
  for (int r = 0; r < 4; ++r) {
    const int k = kbase + r;
    const uint2* Ep = (const uint2*)(E8 + ((size_t)cb * SEQ + k) * SEQ);
    float s = 0.f;
#pragma unroll
    for (int it = 0; it < 4; ++it) {
      const uint2 v = Ep[it * 64 + lane];
      const float* rz = (const float*)&rzv[it][0];
      s += __builtin_amdgcn_cvt_f32_fp8(v.x, 0) * rz[0];
      s += __builtin_amdgcn_cvt_f32_fp8(v.x, 1) * rz[1];
      s += __builtin_amdgcn_cvt_f32_fp8(v.x, 2) * rz[2];
      s += __builtin_amdgcn_cvt_f32_fp8(v.x, 3) * rz[3];
      s += __builtin_amdgcn_cvt_f32_fp8(v.y, 0) * rz[4];
      s += __builtin_amdgcn_cvt_f32_fp8(v.y, 1) * rz[5];
      s += __builtin_amdgcn_cvt_f32_fp8(v.y, 2) * rz[6];
      s += __builtin_amdgcn_cvt_f32_fp8(v.y, 3) * rz[7];
    }
    s += __shfl_down(s, 32); s += __shfl_down(s, 16); s += __shfl_down(s, 8);
    s += __shfl_down(s, 4);  s += __shfl_down(s, 2);  s += __shfl_down(s, 1);
    if (lane == 0) wout[(size_t)cb * SEQ + k] = s;
  }
}

// sumw_all[b] = sum_k w[k]
__global__ void sumw_kernel(const float* __restrict__ w,
                            float* __restrict__ sumw_all, int b0) {
  __shared__ float sred[4];
  const int t = threadIdx.x, lane = t & 63, wave = t >> 6;
  const int cb = blockIdx.x;
  float v = 0.f;
  for (int k = t; k < SEQ; k += 256) v += w[(size_t)cb * SEQ + k];
  v += __shfl_down(v, 32); v += __shfl_down(v, 16); v += __shfl_down(v, 8);
  v += __shfl_down(v, 4);  v += __shfl_down(v, 2);  v += __shfl_down(v, 1);
  if (lane == 0) sred[wave] = v;
  __syncthreads();
  if (t == 0) sumw_all[b0 + cb] = sred[0] + sred[1] + sred[2] + sred[3];
}

// wxp[kq][b][d] = (1/32) * sum_{k in chunk kq} w[k] * x8[b][k][d]
__global__ __launch_bounds__(256)
void wxpart_kernel(const uint8_t* __restrict__ x8,
                   const float* __restrict__ w,
                   float* __restrict__ wxp, int b0) {
  const int cb = blockIdx.y, kq = blockIdx.z;
  const int b = b0 + cb;
  const int d4 = threadIdx.x;  // 4 d's per thread
  const uint8_t* xb =
      x8 + ((size_t)b * SEQ + (size_t)kq * (SEQ / KSPLIT)) * DMODEL;
  const float* wb = w + (size_t)cb * SEQ + (size_t)kq * (SEQ / KSPLIT);
  float a0 = 0.f, a1 = 0.f, a2 = 0.f, a3 = 0.f;
#pragma unroll 4
  for (int k = 0; k < SEQ / KSPLIT; ++k) {
    const float wk = wb[k];
    const uint32_t pv = *(const uint32_t*)(xb + (size_t)k * DMODEL + d4 * 4);
    a0 += wk * (float)(int8_t)(pv & 0xff);
    a1 += wk * (float)(int8_t)((pv >> 8) & 0xff);
    a2 += wk * (float)(int8_t)((pv >> 16) & 0xff);
    a3 += wk * (float)(int8_t)(pv >> 24);
  }
  float4* o = (float4*)&wxp[((size_t)kq * NBATCH + b) * DMODEL + d4 * 4];
  *o = make_float4(a0 * 0.03125f, a1 * 0.03125f, a2 * 0.03125f, a3 * 0.03125f);
}

// out[b][e] = ( sum_d (sum_kq wxp) * Wv[e][d] + sumw[b]*bv[e] ) / SEQ
__global__ void final_kernel(const float* __restrict__ wxp,
                             const float* __restrict__ sumw_all,
                             const float* __restrict__ Wv,
                             const float* __restrict__ bv,
                             float* __restrict__ out) {
  const int b = blockIdx.y, eg = blockIdx.x;
  const int wave = threadIdx.x >> 6, lane = threadIdx.x & 63;
  const int e = eg * 4 + wave;
  float acc = 0.f;
  for (int d = lane; d < DMODEL; d += 64) {
    float wx = 0.f;
#pragma unroll
    for (int kq = 0; kq < KSPLIT; ++kq)
      wx += wxp[((size_t)kq * NBATCH + b) * DMODEL + d];
    acc += wx * Wv[(size_t)e * DMODEL + d];
  }
  acc += __shfl_down(acc, 32); acc += __shfl_down(acc, 16);
  acc += __shfl_down(acc, 8);  acc += __shfl_down(acc, 4);
  acc += __shfl_down(acc, 2);  acc += __shfl_down(acc, 1);
  if (lane == 0)
    out[(size_t)b * DMODEL + e] =
        (acc + sumw_all[b] * bv[e]) * (1.f / (float)SEQ);
}

// ---------------------------------------------------------------------------
extern "C" void kernel_launch(void* const* d_in, const int* in_sizes, int n_in,
                              void* d_out, int out_size, void* d_ws, size_t ws_size,
                              hipStream_t stream) {
  const float* x  = (const float*)d_in[0];
  const int* mask = (const int*)d_in[1];
  const float* Wq = (const float*)d_in[2];
  const float* bq = (const float*)d_in[3];
  const float* Wk = (const float*)d_in[4];
  const float* bk = (const float*)d_in[5];
  const float* Wv = (const float*)d_in[6];
  const float* bv = (const float*)d_in[7];
  float* out = (float*)d_out;
  (void)bk;

  char* ws = (char*)d_ws;
  size_t off = 0;
  auto alloc = [&](size_t bytes) -> void* {
    void* p = ws + off;
    off += (bytes + 255) & ~(size_t)255;
    return p;
  };
  // ---- persistent ----
  uint8_t* Mt8 = (uint8_t*)alloc((size_t)DMODEL * DMODEL);
  __hip_bfloat16* WqT_bf = (__hip_bfloat16*)alloc((size_t)DMODEL * DMODEL * 2);
  __hip_bfloat16* WkT_bf = (__hip_bfloat16*)alloc((size_t)DMODEL * DMODEL * 2);
  float* wxp      = (float*)alloc((size_t)KSPLIT * NBATCH * DMODEL * 4);
  float* sumw_all = (float*)alloc((size_t)NBATCH * 4);
  float* t2       = (float*)alloc((size_t)DMODEL * 4);
  uint8_t* x8i = (uint8_t*)alloc((size_t)NBATCH * SEQ * DMODEL);
  uint8_t* Y8i = (uint8_t*)alloc((size_t)NBATCH * SEQ * DMODEL);
  float* vb = (float*)alloc((size_t)NBATCH * SEQ * 4);
  const size_t fixed = off;

  // ---- per-chunk ----
  const size_t per_batch = (size_t)SEQ * SEQ      // E (fp8)
                         + (size_t)8 * SEQ * 4    // Zpart
                         + (size_t)2 * SEQ * 4 + 8 * 256;
  long avail = (long)ws_size - (long)fixed;
  int NB = (int)(avail / (long)per_batch);
  if (NB < 1) NB = 1;
  if (NB > NBATCH) NB = NBATCH;
  while (NBATCH % NB) --NB;
  uint8_t* Ebuf = (uint8_t*)alloc((size_t)NB * SEQ * SEQ);
  float* Zpart = (float*)alloc((size_t)NB * 8 * SEQ * 4);
  float* rZ    = (float*)alloc((size_t)NB * SEQ * 4);
  float* wbuf  = (float*)alloc((size_t)NB * SEQ * 4);

  // ---- prep ----
  transpose_cvt_kernel<<<dim3(32, 32), dim3(256), 0, stream>>>(Wq, WqT_bf);
  transpose_cvt_kernel<<<dim3(32, 32), dim3(256), 0, stream>>>(Wk, WkT_bf);
  // Mt8[d'][d] = round(1024 * sum_e WkT[d'][e]*WqT[d][e])
  gemmT_kernel<1><<<dim3(4, 4), dim3(512), 0, stream>>>(
      WqT_bf, WkT_bf, Mt8, DMODEL);
  prep_t2_kernel<<<dim3(256), dim3(256), 0, stream>>>(WkT_bf, bq, t2);
  cvtv_kernel<<<dim3(NBATCH * SEQ / 4), dim3(256), 0, stream>>>(
      x, t2, mask, x8i, vb);
  // Y8i[q][d'] = round( (x8 . Mt8) / 1024 )  == round(32*Y)
  i8gemm_kernel<0, 2><<<dim3(NBATCH * SEQ / 512, DMODEL / 256), dim3(512), 0,
                        stream>>>(x8i, Mt8, Y8i, nullptr, nullptr, 0);

  for (int b0 = 0; b0 < NBATCH; b0 += NB) {
    const int nb = NB;
    i8gemm_kernel<1, 4><<<dim3(16, nb), dim3(512), 0, stream>>>(
        x8i, Y8i, Ebuf, vb, Zpart, b0);
    zinv_kernel<<<dim3((nb * SEQ + 255) / 256), dim3(256), 0, stream>>>(
        Zpart, rZ, nb * SEQ);
    passB_kernel<<<dim3(SEQ / 16, nb), dim3(256), 0, stream>>>(Ebuf, rZ, wbuf);
    sumw_kernel<<<dim3(nb), dim3(256), 0, stream>>>(wbuf, sumw_all, b0);
    wxpart_kernel<<<dim3(1, nb, KSPLIT), dim3(256), 0, stream>>>(
        x8i, wbuf, wxp, b0);
  }
  final_kernel<<<dim3(DMODEL / 4, NBATCH), dim3(256), 0, stream>>>(
      wxp, sumw_all, Wv, bv, out);
}